// Round 1
// baseline (120113.916 us; speedup 1.0000x reference)
//
#include <hip/hip_runtime.h>
#include <hip/hip_cooperative_groups.h>

namespace cg = cooperative_groups;

#define G    128
#define P    130
#define P2   (P * P)            // 16900
#define NPAD (P * P * P)        // 2,197,000
#define NG   (G * G * G)        // 2,097,152
#define NB   1024
#define NT   256
#define TOT  (NB * NT)          // 262,144  -> exactly 8 interior cells/thread

__global__ __launch_bounds__(NT, 4)
void sor_kernel(const float* __restrict__ img, const int* __restrict__ sinkp,
                float* __restrict__ v, unsigned char* __restrict__ mask,
                float* __restrict__ partB, float* __restrict__ partR,
                float* __restrict__ out)
{
    cg::grid_group grid = cg::this_grid();
    const int tid = (int)(blockIdx.x * NT + threadIdx.x);
    const float wopt = (float)(2.0 / (1.0 + 3.14159265358979323846 / 130.0));
    const float sinkf = (float)(*sinkp);

    // ---- init: padded v (sink -> 1, else 0), interior mask (0 / 1=black / 2=red) ----
    for (int p = tid; p < NPAD; p += TOT) {
        int i = p / P2;
        int r = p - i * P2;
        int j = r / P;
        int k = r - j * P;
        float vv = 0.0f;
        if (i > 0 && i < P - 1 && j > 0 && j < P - 1 && k > 0 && k < P - 1) {
            float lab = img[(i - 1) * (G * G) + (j - 1) * G + (k - 1)];
            vv = (lab == sinkf) ? 1.0f : 0.0f;
        }
        v[p] = vv;
    }
    for (int g = tid; g < NG; g += TOT) {
        float lab = img[g];
        unsigned char m = 0;
        if (lab == 1.0f) {
            int i = g >> 14, j = (g >> 7) & 127, k = g & 127;
            // padded parity (i+1)+(j+1)+(k+1): even -> black(1), odd -> red(2)
            m = ((i + j + k) & 1) ? 1 : 2;
        }
        mask[g] = m;
    }
    grid.sync();

    __shared__ float sred[NT];
    int it = 0;
    float dv = 0.0f;

    do {
        const int buf = (it & 1) * NB;

        // ---------- black half-sweep ----------
        float loc = 0.0f;
        for (int g = tid; g < NG; g += TOT) {
            if (mask[g] == 1) {
                int i = g >> 14, j = (g >> 7) & 127, k = g & 127;
                int p = (i + 1) * P2 + (j + 1) * P + (k + 1);
                float vc = v[p];
                // exact reference order: ((((v[+1]+v[-1])+v[+P])+v[-P])+v[+P2])+v[-P2]
                float s = __fadd_rn(v[p + 1], v[p - 1]);
                s = __fadd_rn(s, v[p + P]);
                s = __fadd_rn(s, v[p - P]);
                s = __fadd_rn(s, v[p + P2]);
                s = __fadd_rn(s, v[p - P2]);
                float t = __fsub_rn(s, __fmul_rn(6.0f, vc));
                float adj = __fdiv_rn(__fmul_rn(wopt, t), 6.0f);
                v[p] = __fadd_rn(vc, adj);
                loc += fabsf(adj);
            }
        }
        sred[threadIdx.x] = loc;
        __syncthreads();
        for (int st = NT / 2; st > 0; st >>= 1) {
            if ((int)threadIdx.x < st) sred[threadIdx.x] += sred[threadIdx.x + st];
            __syncthreads();
        }
        if (threadIdx.x == 0) partB[buf + blockIdx.x] = sred[0];
        __syncthreads();
        grid.sync();   // black updates + partB visible everywhere

        // ---------- red half-sweep ----------
        loc = 0.0f;
        for (int g = tid; g < NG; g += TOT) {
            if (mask[g] == 2) {
                int i = g >> 14, j = (g >> 7) & 127, k = g & 127;
                int p = (i + 1) * P2 + (j + 1) * P + (k + 1);
                float vc = v[p];
                float s = __fadd_rn(v[p + 1], v[p - 1]);
                s = __fadd_rn(s, v[p + P]);
                s = __fadd_rn(s, v[p - P]);
                s = __fadd_rn(s, v[p + P2]);
                s = __fadd_rn(s, v[p - P2]);
                float t = __fsub_rn(s, __fmul_rn(6.0f, vc));
                float adj = __fdiv_rn(__fmul_rn(wopt, t), 6.0f);
                v[p] = __fadd_rn(vc, adj);
                loc += fabsf(adj);
            }
        }
        sred[threadIdx.x] = loc;
        __syncthreads();
        for (int st = NT / 2; st > 0; st >>= 1) {
            if ((int)threadIdx.x < st) sred[threadIdx.x] += sred[threadIdx.x + st];
            __syncthreads();
        }
        if (threadIdx.x == 0) partR[buf + blockIdx.x] = sred[0];
        __syncthreads();
        grid.sync();   // red updates + partR visible everywhere

        // ---------- every block redundantly reduces dv (no 3rd grid sync) ----------
        float a = 0.0f;
        for (int q = (int)threadIdx.x; q < NB; q += NT) a += partB[buf + q];
        for (int q = (int)threadIdx.x; q < NB; q += NT) a += partR[buf + q];
        sred[threadIdx.x] = a;
        __syncthreads();
        for (int st = NT / 2; st > 0; st >>= 1) {
            if ((int)threadIdx.x < st) sred[threadIdx.x] += sred[threadIdx.x + st];
            __syncthreads();
        }
        dv = sred[0];          // identical (fixed-order) in every block/thread
        __syncthreads();       // protect sred reuse next iteration

        ++it;
    } while (dv >= 0.05f && it <= 500);

    // ---------- epilogue: interior extraction + scalars ----------
    for (int g = tid; g < NG; g += TOT) {
        int i = g >> 14, j = (g >> 7) & 127, k = g & 127;
        out[g] = v[(i + 1) * P2 + (j + 1) * P + (k + 1)];
    }
    if (tid == 0) {
        out[NG]     = (float)it;
        out[NG + 1] = dv;
    }
}

extern "C" void kernel_launch(void* const* d_in, const int* in_sizes, int n_in,
                              void* d_out, int out_size, void* d_ws, size_t ws_size,
                              hipStream_t stream) {
    const float* img  = (const float*)d_in[0];
    const int*   sink = (const int*)d_in[2];   // sink_label (=3)
    float*       out  = (float*)d_out;

    char* ws = (char*)d_ws;
    size_t off = 0;
    float* v = (float*)(ws + off);
    off += (size_t)NPAD * sizeof(float);
    off = (off + 255) & ~(size_t)255;
    unsigned char* mask = (unsigned char*)(ws + off);
    off += (size_t)NG;
    off = (off + 255) & ~(size_t)255;
    float* partB = (float*)(ws + off);
    off += (size_t)2 * NB * sizeof(float);
    float* partR = (float*)(ws + off);
    off += (size_t)2 * NB * sizeof(float);
    (void)ws_size; (void)in_sizes; (void)n_in; (void)out_size;

    void* args[] = { (void*)&img, (void*)&sink, (void*)&v, (void*)&mask,
                     (void*)&partB, (void*)&partR, (void*)&out };
    hipLaunchCooperativeKernel((const void*)sor_kernel, dim3(NB), dim3(NT),
                               args, 0, stream);
}

// Round 2
// 65189.783 us; speedup vs baseline: 1.8425x; 1.8425x over previous
//
#include <hip/hip_runtime.h>
#include <hip/hip_cooperative_groups.h>

namespace cg = cooperative_groups;

#define G    128
#define GG   (G * G)
#define P    130
#define P2   (P * P)
#define NPAD (P * P * P)        // 2,197,000
#define NG   (G * G * G)        // 2,097,152
#define NB   512
#define NT   256
#define TOT  (NB * NT)          // 131,072
#define CH   (NG / NB)          // 4096 cells per block
#define CT   (CH / NT)          // 16 cells per thread
#define CAPC (640 * 1024)       // per-color list capacity (actives ~262K/color)

__global__ __launch_bounds__(NT, 4)
void sor_kernel(const float* __restrict__ img, const int* __restrict__ sinkp,
                float* __restrict__ v, int* __restrict__ listB, int* __restrict__ listR,
                int* __restrict__ cntB, int* __restrict__ cntR,
                float* __restrict__ partB, float* __restrict__ partR,
                float* __restrict__ out)
{
    cg::grid_group grid = cg::this_grid();
    const int t   = (int)threadIdx.x;
    const int b   = (int)blockIdx.x;
    const int tid = b * NT + t;
    const float wopt  = (float)(2.0 / (1.0 + 3.14159265358979323846 / 130.0));
    const float sinkf = (float)(*sinkp);

    __shared__ int   sB[NT], sR[NT];
    __shared__ float sred[NT];
    __shared__ int   shN[4];   // baseB, baseR, nBtot, nRtot

    // ---- init padded v: sink -> 1, else 0 ----
    for (int p = tid; p < NPAD; p += TOT) {
        int i = p / P2;
        int r = p - i * P2;
        int j = r / P;
        int k = r - j * P;
        float vv = 0.0f;
        if (i > 0 && i < P - 1 && j > 0 && j < P - 1 && k > 0 && k < P - 1) {
            float lab = img[(i - 1) * GG + (j - 1) * G + (k - 1)];
            vv = (lab == sinkf) ? 1.0f : 0.0f;
        }
        v[p] = vv;
    }

    // ---- per-thread active counts over its contiguous 16-cell chunk ----
    const int g0 = b * CH + t * CT;
    int cB = 0, cR = 0;
    for (int q = 0; q < CT; ++q) {
        float lab = img[g0 + q];
        if (lab == 1.0f) {
            int g = g0 + q;
            int par = ((g >> 14) + ((g >> 7) & 127) + (g & 127)) & 1;
            if (par) cB++; else cR++;   // unpadded odd == padded even == black
        }
    }
    // intra-block inclusive scan (Hillis-Steele)
    sB[t] = cB; sR[t] = cR;
    __syncthreads();
    for (int off = 1; off < NT; off <<= 1) {
        int aB = 0, aR = 0;
        if (t >= off) { aB = sB[t - off]; aR = sR[t - off]; }
        __syncthreads();
        if (t >= off) { sB[t] += aB; sR[t] += aR; }
        __syncthreads();
    }
    const int exB = sB[t] - cB;
    const int exR = sR[t] - cR;
    if (t == NT - 1) { cntB[b] = sB[t]; cntR[b] = sR[t]; }
    grid.sync();

    // ---- block base offsets + totals (deterministic, every block redundantly) ----
    {
        int mB = 0, mR = 0, tB = 0, tR = 0;
        for (int e = t; e < NB; e += NT) {
            int vb = cntB[e], vr = cntR[e];
            tB += vb; tR += vr;
            if (e < b) { mB += vb; mR += vr; }
        }
        sB[t] = mB; sR[t] = mR;
        __syncthreads();
        for (int st = NT / 2; st > 0; st >>= 1) {
            if (t < st) { sB[t] += sB[t + st]; sR[t] += sR[t + st]; }
            __syncthreads();
        }
        if (t == 0) { shN[0] = sB[0]; shN[1] = sR[0]; }
        __syncthreads();
        sB[t] = tB; sR[t] = tR;
        __syncthreads();
        for (int st = NT / 2; st > 0; st >>= 1) {
            if (t < st) { sB[t] += sB[t + st]; sR[t] += sR[t + st]; }
            __syncthreads();
        }
        if (t == 0) { shN[2] = sB[0]; shN[3] = sR[0]; }
        __syncthreads();
    }
    const int baseB = shN[0], baseR = shN[1];
    const int nBt = shN[2], nRt = shN[3];

    // ---- write compacted lists (global cell order preserved -> deterministic) ----
    {
        int pB = baseB + exB, pR = baseR + exR;
        for (int q = 0; q < CT; ++q) {
            int g = g0 + q;
            float lab = img[g];
            if (lab == 1.0f) {
                int i = g >> 14, j = (g >> 7) & 127, k = g & 127;
                int p = (i + 1) * P2 + (j + 1) * P + (k + 1);
                if ((i + j + k) & 1) listB[pB++] = p; else listR[pR++] = p;
            }
        }
    }
    grid.sync();

    // ---- SOR loop ----
    // exact reference numerics per cell:
    // s = ((((v[+1]+v[-1])+v[+P])+v[-P])+v[+P2])+v[-P2]
    // adj = (wopt * (s - 6*v)) / 6 ; v += adj
#define SWEEP(LIST, NTOT, PART)                                            \
    {                                                                      \
        float loc = 0.0f;                                                  \
        int x = tid;                                                       \
        for (; x + TOT < (NTOT); x += 2 * TOT) {                           \
            const int pa = LIST[x], pb = LIST[x + TOT];                    \
            float va0 = v[pa],      vb0 = v[pb];                           \
            float a1 = v[pa + 1],   b1 = v[pb + 1];                        \
            float a2 = v[pa - 1],   b2 = v[pb - 1];                        \
            float a3 = v[pa + P],   b3 = v[pb + P];                        \
            float a4 = v[pa - P],   b4 = v[pb - P];                        \
            float a5 = v[pa + P2],  b5 = v[pb + P2];                       \
            float a6 = v[pa - P2],  b6 = v[pb - P2];                       \
            float sa = __fadd_rn(a1, a2);                                  \
            sa = __fadd_rn(sa, a3); sa = __fadd_rn(sa, a4);                \
            sa = __fadd_rn(sa, a5); sa = __fadd_rn(sa, a6);                \
            float sb = __fadd_rn(b1, b2);                                  \
            sb = __fadd_rn(sb, b3); sb = __fadd_rn(sb, b4);                \
            sb = __fadd_rn(sb, b5); sb = __fadd_rn(sb, b6);                \
            float ta = __fsub_rn(sa, __fmul_rn(6.0f, va0));                \
            float tb = __fsub_rn(sb, __fmul_rn(6.0f, vb0));                \
            float adja = __fdiv_rn(__fmul_rn(wopt, ta), 6.0f);             \
            float adjb = __fdiv_rn(__fmul_rn(wopt, tb), 6.0f);             \
            v[pa] = __fadd_rn(va0, adja);                                  \
            v[pb] = __fadd_rn(vb0, adjb);                                  \
            loc += fabsf(adja); loc += fabsf(adjb);                        \
        }                                                                  \
        for (; x < (NTOT); x += TOT) {                                     \
            const int p = LIST[x];                                         \
            float vc = v[p];                                               \
            float s = __fadd_rn(v[p + 1], v[p - 1]);                       \
            s = __fadd_rn(s, v[p + P]);  s = __fadd_rn(s, v[p - P]);       \
            s = __fadd_rn(s, v[p + P2]); s = __fadd_rn(s, v[p - P2]);      \
            float tt = __fsub_rn(s, __fmul_rn(6.0f, vc));                  \
            float adj = __fdiv_rn(__fmul_rn(wopt, tt), 6.0f);              \
            v[p] = __fadd_rn(vc, adj);                                     \
            loc += fabsf(adj);                                             \
        }                                                                  \
        sred[t] = loc;                                                     \
        __syncthreads();                                                   \
        for (int st = NT / 2; st > 0; st >>= 1) {                          \
            if (t < st) sred[t] += sred[t + st];                           \
            __syncthreads();                                               \
        }                                                                  \
        if (t == 0) PART[buf + b] = sred[0];                               \
        __syncthreads();                                                   \
    }

    int it = 0;
    float dv = 0.0f;
    do {
        const int buf = (it & 1) * NB;

        SWEEP(listB, nBt, partB)
        grid.sync();                 // black updates + partB visible

        SWEEP(listR, nRt, partR)
        grid.sync();                 // red updates + partR visible

        // every block redundantly reduces dv (fixed order -> identical result)
        float a = 0.0f;
        for (int q = t; q < NB; q += NT) a += partB[buf + q];
        for (int q = t; q < NB; q += NT) a += partR[buf + q];
        sred[t] = a;
        __syncthreads();
        for (int st = NT / 2; st > 0; st >>= 1) {
            if (t < st) sred[t] += sred[t + st];
            __syncthreads();
        }
        dv = sred[0];
        __syncthreads();

        ++it;
    } while (dv >= 0.05f && it <= 500);

    // ---- epilogue ----
    for (int g = tid; g < NG; g += TOT) {
        int i = g >> 14, j = (g >> 7) & 127, k = g & 127;
        out[g] = v[(i + 1) * P2 + (j + 1) * P + (k + 1)];
    }
    if (tid == 0) {
        out[NG]     = (float)it;
        out[NG + 1] = dv;
    }
}

extern "C" void kernel_launch(void* const* d_in, const int* in_sizes, int n_in,
                              void* d_out, int out_size, void* d_ws, size_t ws_size,
                              hipStream_t stream) {
    const float* img  = (const float*)d_in[0];
    const int*   sink = (const int*)d_in[2];   // sink_label (=3)
    float*       out  = (float*)d_out;

    char* ws = (char*)d_ws;
    size_t off = 0;
    float* v = (float*)(ws + off);
    off += (size_t)NPAD * sizeof(float);
    off = (off + 255) & ~(size_t)255;
    int* listB = (int*)(ws + off);
    off += (size_t)CAPC * sizeof(int);
    int* listR = (int*)(ws + off);
    off += (size_t)CAPC * sizeof(int);
    int* cntB = (int*)(ws + off);
    off += (size_t)NB * sizeof(int);
    int* cntR = (int*)(ws + off);
    off += (size_t)NB * sizeof(int);
    float* partB = (float*)(ws + off);
    off += (size_t)2 * NB * sizeof(float);
    float* partR = (float*)(ws + off);
    off += (size_t)2 * NB * sizeof(float);
    (void)ws_size; (void)in_sizes; (void)n_in; (void)out_size;

    void* args[] = { (void*)&img, (void*)&sink, (void*)&v,
                     (void*)&listB, (void*)&listR, (void*)&cntB, (void*)&cntR,
                     (void*)&partB, (void*)&partR, (void*)&out };
    hipLaunchCooperativeKernel((const void*)sor_kernel, dim3(NB), dim3(NT),
                               args, 0, stream);
}

// Round 3
// 60394.434 us; speedup vs baseline: 1.9888x; 1.0794x over previous
//
#include <hip/hip_runtime.h>
#include <hip/hip_cooperative_groups.h>

namespace cg = cooperative_groups;

#define G    128
#define GG   (G * G)
#define P    130
#define P2   (P * P)
#define NPAD (P * P * P)        // 2,197,000
#define NG   (G * G * G)        // 2,097,152
#define NB   512
#define NT   256
#define TOT  (NB * NT)          // 131,072
#define CH   (NG / NB)          // 4096 cells per block
#define CT   (CH / NT)          // 16 cells per thread
#define CAPC (640 * 1024)
#define SAFEP (P2 + P + 1)      // harmless interior index for inactive slots

// ---- fast distributed grid barrier ----
// arrival: agent-scope atomic store (bypasses L2 -> no dirty-line false sharing)
// poll: all-to-all, each thread polls 2 flags; fences: release-wb before, acquire-inv after
__device__ inline void gbar(int* __restrict__ flags, int phase, int b, int t) {
    __syncthreads();
    __builtin_amdgcn_fence(__ATOMIC_RELEASE, "agent");
    if (t == 0)
        __hip_atomic_store(&flags[b], phase, __ATOMIC_RELAXED, __HIP_MEMORY_SCOPE_AGENT);
    while (__hip_atomic_load(&flags[t], __ATOMIC_RELAXED, __HIP_MEMORY_SCOPE_AGENT) < phase)
        __builtin_amdgcn_s_sleep(1);
    while (__hip_atomic_load(&flags[t + NT], __ATOMIC_RELAXED, __HIP_MEMORY_SCOPE_AGENT) < phase)
        __builtin_amdgcn_s_sleep(1);
    __builtin_amdgcn_fence(__ATOMIC_ACQUIRE, "agent");
    __syncthreads();
}

// block reduce: wave64 shuffle + 4-slot LDS combine (deterministic fixed order)
__device__ inline float bred(float x, int t, float* s4) {
    for (int o = 32; o; o >>= 1) x += __shfl_down(x, o, 64);
    __syncthreads();                       // protect s4 from previous use
    if ((t & 63) == 0) s4[t >> 6] = x;
    __syncthreads();
    return ((s4[0] + s4[1]) + s4[2]) + s4[3];
}

__global__ __launch_bounds__(NT, 4)
void sor_kernel(const float* __restrict__ img, const int* __restrict__ sinkp,
                float* __restrict__ v, int* __restrict__ listB, int* __restrict__ listR,
                int* __restrict__ cntB, int* __restrict__ cntR,
                float* __restrict__ partB, float* __restrict__ partR,
                int* __restrict__ flags, float* __restrict__ out)
{
    cg::grid_group grid = cg::this_grid();
    const int t   = (int)threadIdx.x;
    const int b   = (int)blockIdx.x;
    const int tid = b * NT + t;
    const float wopt  = (float)(2.0 / (1.0 + 3.14159265358979323846 / 130.0));
    const float sinkf = (float)(*sinkp);

    __shared__ int   sB[NT], sR[NT];
    __shared__ float s4[4];
    __shared__ int   shN[4];   // baseB, baseR, nBtot, nRtot

    // reset barrier flags (ws not re-poisoned between replays -> must self-init)
    if (t == 0)
        __hip_atomic_store(&flags[b], 0, __ATOMIC_RELAXED, __HIP_MEMORY_SCOPE_AGENT);

    // ---- init padded v: sink -> 1, else 0 ----
    for (int p = tid; p < NPAD; p += TOT) {
        int i = p / P2;
        int r = p - i * P2;
        int j = r / P;
        int k = r - j * P;
        float vv = 0.0f;
        if (i > 0 && i < P - 1 && j > 0 && j < P - 1 && k > 0 && k < P - 1) {
            float lab = img[(i - 1) * GG + (j - 1) * G + (k - 1)];
            vv = (lab == sinkf) ? 1.0f : 0.0f;
        }
        v[p] = vv;
    }

    // ---- per-thread active counts over contiguous 16-cell chunk ----
    const int g0 = b * CH + t * CT;
    int cB = 0, cR = 0;
    for (int q = 0; q < CT; ++q) {
        float lab = img[g0 + q];
        if (lab == 1.0f) {
            int g = g0 + q;
            int par = ((g >> 14) + ((g >> 7) & 127) + (g & 127)) & 1;
            if (par) cB++; else cR++;
        }
    }
    sB[t] = cB; sR[t] = cR;
    __syncthreads();
    for (int off = 1; off < NT; off <<= 1) {
        int aB = 0, aR = 0;
        if (t >= off) { aB = sB[t - off]; aR = sR[t - off]; }
        __syncthreads();
        if (t >= off) { sB[t] += aB; sR[t] += aR; }
        __syncthreads();
    }
    const int exB = sB[t] - cB;
    const int exR = sR[t] - cR;
    if (t == NT - 1) { cntB[b] = sB[t]; cntR[b] = sR[t]; }
    grid.sync();

    // ---- block base offsets + totals (redundant, deterministic) ----
    {
        int mB = 0, mR = 0, tB = 0, tR = 0;
        for (int e = t; e < NB; e += NT) {
            int vb = cntB[e], vr = cntR[e];
            tB += vb; tR += vr;
            if (e < b) { mB += vb; mR += vr; }
        }
        sB[t] = mB; sR[t] = mR;
        __syncthreads();
        for (int st = NT / 2; st > 0; st >>= 1) {
            if (t < st) { sB[t] += sB[t + st]; sR[t] += sR[t + st]; }
            __syncthreads();
        }
        if (t == 0) { shN[0] = sB[0]; shN[1] = sR[0]; }
        __syncthreads();
        sB[t] = tB; sR[t] = tR;
        __syncthreads();
        for (int st = NT / 2; st > 0; st >>= 1) {
            if (t < st) { sB[t] += sB[t + st]; sR[t] += sR[t + st]; }
            __syncthreads();
        }
        if (t == 0) { shN[2] = sB[0]; shN[3] = sR[0]; }
        __syncthreads();
    }
    const int baseB = shN[0], baseR = shN[1];
    const int nBt = shN[2], nRt = shN[3];

    // ---- write compacted lists (global cell order -> deterministic) ----
    {
        int pB = baseB + exB, pR = baseR + exR;
        for (int q = 0; q < CT; ++q) {
            int g = g0 + q;
            float lab = img[g];
            if (lab == 1.0f) {
                int i = g >> 14, j = (g >> 7) & 127, k = g & 127;
                int p = (i + 1) * P2 + (j + 1) * P + (k + 1);
                if ((i + j + k) & 1) listB[pB++] = p; else listR[pR++] = p;
            }
        }
    }
    grid.sync();

    // ---- hoist this thread's cells into registers (3 slots/color + rare tail) ----
    int pb0 = (tid < nBt)           ? listB[tid]           : -1;
    int pb1 = (tid + TOT < nBt)     ? listB[tid + TOT]     : -1;
    int pb2 = (tid + 2 * TOT < nBt) ? listB[tid + 2 * TOT] : -1;
    int pr0 = (tid < nRt)           ? listR[tid]           : -1;
    int pr1 = (tid + TOT < nRt)     ? listR[tid + TOT]     : -1;
    int pr2 = (tid + 2 * TOT < nRt) ? listR[tid + 2 * TOT] : -1;

    // exact reference numerics per cell:
    // s = ((((v[+1]+v[-1])+v[+P])+v[-P])+v[+P2])+v[-P2]
    // adj = (wopt * (s - 6*v)) / 6 ; v += adj
#define CELL1(p, loc)                                                     \
    {                                                                     \
        float vc = v[p];                                                  \
        float s = __fadd_rn(v[(p) + 1], v[(p) - 1]);                      \
        s = __fadd_rn(s, v[(p) + P]);  s = __fadd_rn(s, v[(p) - P]);      \
        s = __fadd_rn(s, v[(p) + P2]); s = __fadd_rn(s, v[(p) - P2]);     \
        float tt = __fsub_rn(s, __fmul_rn(6.0f, vc));                     \
        float adj = __fdiv_rn(__fmul_rn(wopt, tt), 6.0f);                 \
        v[p] = __fadd_rn(vc, adj);                                        \
        loc += fabsf(adj);                                                \
    }

#define SWEEP3(c0, c1, c2, LIST, NTOT, PART)                               \
    {                                                                      \
        float loc = 0.0f;                                                  \
        const int q0 = (c0 >= 0) ? c0 : SAFEP;                             \
        const int q1 = (c1 >= 0) ? c1 : SAFEP;                             \
        const int q2 = (c2 >= 0) ? c2 : SAFEP;                             \
        float vc0 = v[q0],      vc1 = v[q1],      vc2 = v[q2];             \
        float a1 = v[q0 + 1],   b1 = v[q1 + 1],   e1 = v[q2 + 1];          \
        float a2 = v[q0 - 1],   b2 = v[q1 - 1],   e2 = v[q2 - 1];          \
        float a3 = v[q0 + P],   b3 = v[q1 + P],   e3 = v[q2 + P];          \
        float a4 = v[q0 - P],   b4 = v[q1 - P],   e4 = v[q2 - P];          \
        float a5 = v[q0 + P2],  b5 = v[q1 + P2],  e5 = v[q2 + P2];         \
        float a6 = v[q0 - P2],  b6 = v[q1 - P2],  e6 = v[q2 - P2];         \
        float sa = __fadd_rn(a1, a2);                                      \
        sa = __fadd_rn(sa, a3); sa = __fadd_rn(sa, a4);                    \
        sa = __fadd_rn(sa, a5); sa = __fadd_rn(sa, a6);                    \
        float sb = __fadd_rn(b1, b2);                                      \
        sb = __fadd_rn(sb, b3); sb = __fadd_rn(sb, b4);                    \
        sb = __fadd_rn(sb, b5); sb = __fadd_rn(sb, b6);                    \
        float se = __fadd_rn(e1, e2);                                      \
        se = __fadd_rn(se, e3); se = __fadd_rn(se, e4);                    \
        se = __fadd_rn(se, e5); se = __fadd_rn(se, e6);                    \
        float ta = __fsub_rn(sa, __fmul_rn(6.0f, vc0));                    \
        float tb = __fsub_rn(sb, __fmul_rn(6.0f, vc1));                    \
        float te = __fsub_rn(se, __fmul_rn(6.0f, vc2));                    \
        float adj0 = __fdiv_rn(__fmul_rn(wopt, ta), 6.0f);                 \
        float adj1 = __fdiv_rn(__fmul_rn(wopt, tb), 6.0f);                 \
        float adj2 = __fdiv_rn(__fmul_rn(wopt, te), 6.0f);                 \
        if (c0 >= 0) { v[q0] = __fadd_rn(vc0, adj0); loc += fabsf(adj0); } \
        if (c1 >= 0) { v[q1] = __fadd_rn(vc1, adj1); loc += fabsf(adj1); } \
        if (c2 >= 0) { v[q2] = __fadd_rn(vc2, adj2); loc += fabsf(adj2); } \
        for (int x = tid + 3 * TOT; x < (NTOT); x += TOT) {                \
            const int p = LIST[x];                                         \
            CELL1(p, loc)                                                  \
        }                                                                  \
        float bs = bred(loc, t, s4);                                       \
        if (t == 0) PART[buf + b] = bs;                                    \
    }

    int it = 0;
    float dv = 0.0f;
    int phase = 0;
    do {
        const int buf = (it & 1) * NB;

        SWEEP3(pb0, pb1, pb2, listB, nBt, partB)
        gbar(flags, ++phase, b, t);          // black updates + partB visible

        SWEEP3(pr0, pr1, pr2, listR, nRt, partR)
        gbar(flags, ++phase, b, t);          // red updates + partR visible

        // every block redundantly reduces dv (fixed order -> identical everywhere)
        float a = ((partB[buf + t] + partB[buf + t + NT])
                 + partR[buf + t]) + partR[buf + t + NT];
        dv = bred(a, t, s4);

        ++it;
    } while (dv >= 0.05f && it <= 500);

    // ---- epilogue ----
    for (int g = tid; g < NG; g += TOT) {
        int i = g >> 14, j = (g >> 7) & 127, k = g & 127;
        out[g] = v[(i + 1) * P2 + (j + 1) * P + (k + 1)];
    }
    if (tid == 0) {
        out[NG]     = (float)it;
        out[NG + 1] = dv;
    }
}

extern "C" void kernel_launch(void* const* d_in, const int* in_sizes, int n_in,
                              void* d_out, int out_size, void* d_ws, size_t ws_size,
                              hipStream_t stream) {
    const float* img  = (const float*)d_in[0];
    const int*   sink = (const int*)d_in[2];   // sink_label (=3)
    float*       out  = (float*)d_out;

    char* ws = (char*)d_ws;
    size_t off = 0;
    float* v = (float*)(ws + off);
    off += (size_t)NPAD * sizeof(float);
    off = (off + 255) & ~(size_t)255;
    int* listB = (int*)(ws + off);
    off += (size_t)CAPC * sizeof(int);
    int* listR = (int*)(ws + off);
    off += (size_t)CAPC * sizeof(int);
    int* cntB = (int*)(ws + off);
    off += (size_t)NB * sizeof(int);
    int* cntR = (int*)(ws + off);
    off += (size_t)NB * sizeof(int);
    float* partB = (float*)(ws + off);
    off += (size_t)2 * NB * sizeof(float);
    float* partR = (float*)(ws + off);
    off += (size_t)2 * NB * sizeof(float);
    off = (off + 255) & ~(size_t)255;
    int* flags = (int*)(ws + off);
    off += (size_t)NB * sizeof(int);
    (void)ws_size; (void)in_sizes; (void)n_in; (void)out_size;

    void* args[] = { (void*)&img, (void*)&sink, (void*)&v,
                     (void*)&listB, (void*)&listR, (void*)&cntB, (void*)&cntR,
                     (void*)&partB, (void*)&partR, (void*)&flags, (void*)&out };
    hipLaunchCooperativeKernel((const void*)sor_kernel, dim3(NB), dim3(NT),
                               args, 0, stream);
}

// Round 4
// 11698.076 us; speedup vs baseline: 10.2678x; 5.1628x over previous
//
#include <hip/hip_runtime.h>
#include <hip/hip_cooperative_groups.h>

namespace cg = cooperative_groups;

#define G    128
#define GG   (G * G)
#define P    130
#define P2   (P * P)
#define NPAD (P * P * P)        // 2,197,000
#define NG   (G * G * G)        // 2,097,152
#define NB   512
#define NT   256
#define TOT  (NB * NT)          // 131,072
#define CH   (NG / NB)          // 4096 cells per block
#define CT   (CH / NT)          // 16 cells per thread
#define CAPC (640 * 1024)
#define SAFEP (P2 + P + 1)      // harmless interior index for inactive slots

// device-scope (MALL-coherent, L1/L2-bypassing) accesses for all loop-shared data
__device__ inline float LDV(const float* p) {
    return __hip_atomic_load((float*)p, __ATOMIC_RELAXED, __HIP_MEMORY_SCOPE_AGENT);
}
__device__ inline void STV(float* p, float x) {
    __hip_atomic_store(p, x, __ATOMIC_RELAXED, __HIP_MEMORY_SCOPE_AGENT);
}

// fence-free grid barrier: drain stores (they're already at the coherence point),
// arrive, wave-0 polls all flags, release block. No cache maintenance at all.
__device__ inline void gbar(int* __restrict__ flags, int phase, int b, int t) {
    asm volatile("s_waitcnt vmcnt(0)" ::: "memory");  // per-wave store drain
    __syncthreads();                                  // all waves drained
    if (t == 0)
        __hip_atomic_store(&flags[b], phase, __ATOMIC_RELAXED, __HIP_MEMORY_SCOPE_AGENT);
    if (t < 64) {
#pragma unroll
        for (int q = 0; q < NB / 64; ++q) {
            while (__hip_atomic_load(&flags[t + 64 * q], __ATOMIC_RELAXED,
                                     __HIP_MEMORY_SCOPE_AGENT) < phase)
                __builtin_amdgcn_s_sleep(1);
        }
    }
    __syncthreads();
    asm volatile("" ::: "memory");                    // no compiler hoisting past poll
}

// block reduce: wave64 shuffle + 4-slot LDS combine (deterministic fixed order)
__device__ inline float bred(float x, int t, float* s4) {
    for (int o = 32; o; o >>= 1) x += __shfl_down(x, o, 64);
    __syncthreads();
    if ((t & 63) == 0) s4[t >> 6] = x;
    __syncthreads();
    return ((s4[0] + s4[1]) + s4[2]) + s4[3];
}

__global__ __launch_bounds__(NT, 4)
void sor_kernel(const float* __restrict__ img, const int* __restrict__ sinkp,
                float* __restrict__ v, int* __restrict__ listB, int* __restrict__ listR,
                int* __restrict__ cntB, int* __restrict__ cntR,
                float* __restrict__ partB, float* __restrict__ partR,
                int* __restrict__ flags, float* __restrict__ out)
{
    cg::grid_group grid = cg::this_grid();
    const int t   = (int)threadIdx.x;
    const int b   = (int)blockIdx.x;
    const int tid = b * NT + t;
    const float wopt  = (float)(2.0 / (1.0 + 3.14159265358979323846 / 130.0));
    const float sinkf = (float)(*sinkp);

    __shared__ int   sB[NT], sR[NT];
    __shared__ float s4[4];
    __shared__ int   shN[4];   // baseB, baseR, nBtot, nRtot

    // reset barrier flag (ws not re-poisoned between replays); the cg grid.sync()s
    // below guarantee every reset lands before any block reaches the first gbar.
    if (t == 0)
        __hip_atomic_store(&flags[b], 0, __ATOMIC_RELAXED, __HIP_MEMORY_SCOPE_AGENT);

    // ---- init padded v: sink -> 1, else 0 ----
    for (int p = tid; p < NPAD; p += TOT) {
        int i = p / P2;
        int r = p - i * P2;
        int j = r / P;
        int k = r - j * P;
        float vv = 0.0f;
        if (i > 0 && i < P - 1 && j > 0 && j < P - 1 && k > 0 && k < P - 1) {
            float lab = img[(i - 1) * GG + (j - 1) * G + (k - 1)];
            vv = (lab == sinkf) ? 1.0f : 0.0f;
        }
        v[p] = vv;
    }

    // ---- per-thread active counts over contiguous 16-cell chunk ----
    const int g0 = b * CH + t * CT;
    int cB = 0, cR = 0;
    for (int q = 0; q < CT; ++q) {
        float lab = img[g0 + q];
        if (lab == 1.0f) {
            int g = g0 + q;
            int par = ((g >> 14) + ((g >> 7) & 127) + (g & 127)) & 1;
            if (par) cB++; else cR++;
        }
    }
    sB[t] = cB; sR[t] = cR;
    __syncthreads();
    for (int off = 1; off < NT; off <<= 1) {
        int aB = 0, aR = 0;
        if (t >= off) { aB = sB[t - off]; aR = sR[t - off]; }
        __syncthreads();
        if (t >= off) { sB[t] += aB; sR[t] += aR; }
        __syncthreads();
    }
    const int exB = sB[t] - cB;
    const int exR = sR[t] - cR;
    if (t == NT - 1) { cntB[b] = sB[t]; cntR[b] = sR[t]; }
    grid.sync();   // full fence: init v + counts globally visible, caches clean

    // ---- block base offsets + totals (redundant, deterministic) ----
    {
        int mB = 0, mR = 0, tB = 0, tR = 0;
        for (int e = t; e < NB; e += NT) {
            int vb = cntB[e], vr = cntR[e];
            tB += vb; tR += vr;
            if (e < b) { mB += vb; mR += vr; }
        }
        sB[t] = mB; sR[t] = mR;
        __syncthreads();
        for (int st = NT / 2; st > 0; st >>= 1) {
            if (t < st) { sB[t] += sB[t + st]; sR[t] += sR[t + st]; }
            __syncthreads();
        }
        if (t == 0) { shN[0] = sB[0]; shN[1] = sR[0]; }
        __syncthreads();
        sB[t] = tB; sR[t] = tR;
        __syncthreads();
        for (int st = NT / 2; st > 0; st >>= 1) {
            if (t < st) { sB[t] += sB[t + st]; sR[t] += sR[t + st]; }
            __syncthreads();
        }
        if (t == 0) { shN[2] = sB[0]; shN[3] = sR[0]; }
        __syncthreads();
    }
    const int baseB = shN[0], baseR = shN[1];
    const int nBt = shN[2], nRt = shN[3];

    // ---- write compacted lists (global cell order -> deterministic) ----
    {
        int pB = baseB + exB, pR = baseR + exR;
        for (int q = 0; q < CT; ++q) {
            int g = g0 + q;
            float lab = img[g];
            if (lab == 1.0f) {
                int i = g >> 14, j = (g >> 7) & 127, k = g & 127;
                int p = (i + 1) * P2 + (j + 1) * P + (k + 1);
                if ((i + j + k) & 1) listB[pB++] = p; else listR[pR++] = p;
            }
        }
    }
    grid.sync();   // full fence: lists visible + all caches clean of v
    // From here on, v/partB/partR are touched ONLY via bypass (agent-scope) ops,
    // so L1/L2 can never hold a stale copy -> no fences needed in the loop.

    // ---- hoist this thread's cells into registers (3 slots/color + rare tail) ----
    int pb0 = (tid < nBt)           ? listB[tid]           : -1;
    int pb1 = (tid + TOT < nBt)     ? listB[tid + TOT]     : -1;
    int pb2 = (tid + 2 * TOT < nBt) ? listB[tid + 2 * TOT] : -1;
    int pr0 = (tid < nRt)           ? listR[tid]           : -1;
    int pr1 = (tid + TOT < nRt)     ? listR[tid + TOT]     : -1;
    int pr2 = (tid + 2 * TOT < nRt) ? listR[tid + 2 * TOT] : -1;

    // exact reference numerics per cell:
    // s = ((((v[+1]+v[-1])+v[+P])+v[-P])+v[+P2])+v[-P2]
    // adj = (wopt * (s - 6*v)) / 6 ; v += adj
#define CELL1(p, loc)                                                     \
    {                                                                     \
        float vc = LDV(&v[p]);                                            \
        float s = __fadd_rn(LDV(&v[(p) + 1]), LDV(&v[(p) - 1]));          \
        s = __fadd_rn(s, LDV(&v[(p) + P]));  s = __fadd_rn(s, LDV(&v[(p) - P]));   \
        s = __fadd_rn(s, LDV(&v[(p) + P2])); s = __fadd_rn(s, LDV(&v[(p) - P2]));  \
        float tt = __fsub_rn(s, __fmul_rn(6.0f, vc));                     \
        float adj = __fdiv_rn(__fmul_rn(wopt, tt), 6.0f);                 \
        STV(&v[p], __fadd_rn(vc, adj));                                   \
        loc += fabsf(adj);                                                \
    }

#define SWEEP3(c0, c1, c2, LIST, NTOT, PART)                               \
    {                                                                      \
        float loc = 0.0f;                                                  \
        const int q0 = (c0 >= 0) ? c0 : SAFEP;                             \
        const int q1 = (c1 >= 0) ? c1 : SAFEP;                             \
        const int q2 = (c2 >= 0) ? c2 : SAFEP;                             \
        float vc0 = LDV(&v[q0]), vc1 = LDV(&v[q1]), vc2 = LDV(&v[q2]);     \
        float a1 = LDV(&v[q0 + 1]),  b1 = LDV(&v[q1 + 1]),  e1 = LDV(&v[q2 + 1]);  \
        float a2 = LDV(&v[q0 - 1]),  b2 = LDV(&v[q1 - 1]),  e2 = LDV(&v[q2 - 1]);  \
        float a3 = LDV(&v[q0 + P]),  b3 = LDV(&v[q1 + P]),  e3 = LDV(&v[q2 + P]);  \
        float a4 = LDV(&v[q0 - P]),  b4 = LDV(&v[q1 - P]),  e4 = LDV(&v[q2 - P]);  \
        float a5 = LDV(&v[q0 + P2]), b5 = LDV(&v[q1 + P2]), e5 = LDV(&v[q2 + P2]); \
        float a6 = LDV(&v[q0 - P2]), b6 = LDV(&v[q1 - P2]), e6 = LDV(&v[q2 - P2]); \
        float sa = __fadd_rn(a1, a2);                                      \
        sa = __fadd_rn(sa, a3); sa = __fadd_rn(sa, a4);                    \
        sa = __fadd_rn(sa, a5); sa = __fadd_rn(sa, a6);                    \
        float sb = __fadd_rn(b1, b2);                                      \
        sb = __fadd_rn(sb, b3); sb = __fadd_rn(sb, b4);                    \
        sb = __fadd_rn(sb, b5); sb = __fadd_rn(sb, b6);                    \
        float se = __fadd_rn(e1, e2);                                      \
        se = __fadd_rn(se, e3); se = __fadd_rn(se, e4);                    \
        se = __fadd_rn(se, e5); se = __fadd_rn(se, e6);                    \
        float ta = __fsub_rn(sa, __fmul_rn(6.0f, vc0));                    \
        float tb = __fsub_rn(sb, __fmul_rn(6.0f, vc1));                    \
        float te = __fsub_rn(se, __fmul_rn(6.0f, vc2));                    \
        float adj0 = __fdiv_rn(__fmul_rn(wopt, ta), 6.0f);                 \
        float adj1 = __fdiv_rn(__fmul_rn(wopt, tb), 6.0f);                 \
        float adj2 = __fdiv_rn(__fmul_rn(wopt, te), 6.0f);                 \
        if (c0 >= 0) { STV(&v[q0], __fadd_rn(vc0, adj0)); loc += fabsf(adj0); } \
        if (c1 >= 0) { STV(&v[q1], __fadd_rn(vc1, adj1)); loc += fabsf(adj1); } \
        if (c2 >= 0) { STV(&v[q2], __fadd_rn(vc2, adj2)); loc += fabsf(adj2); } \
        for (int x = tid + 3 * TOT; x < (NTOT); x += TOT) {                \
            const int p = LIST[x];                                         \
            CELL1(p, loc)                                                  \
        }                                                                  \
        float bs = bred(loc, t, s4);                                       \
        if (t == 0) STV(&PART[buf + b], bs);                               \
    }

    int it = 0;
    float dv = 0.0f;
    int phase = 0;
    do {
        const int buf = (it & 1) * NB;

        SWEEP3(pb0, pb1, pb2, listB, nBt, partB)
        gbar(flags, ++phase, b, t);          // black updates + partB visible

        SWEEP3(pr0, pr1, pr2, listR, nRt, partR)
        gbar(flags, ++phase, b, t);          // red updates + partR visible

        // every block redundantly reduces dv (fixed order -> identical everywhere)
        float a = ((LDV(&partB[buf + t]) + LDV(&partB[buf + t + NT]))
                 + LDV(&partR[buf + t])) + LDV(&partR[buf + t + NT]);
        dv = bred(a, t, s4);

        ++it;
    } while (dv >= 0.05f && it <= 500);

    // ---- epilogue (v read via bypass: L2 holds no valid v lines) ----
    for (int g = tid; g < NG; g += TOT) {
        int i = g >> 14, j = (g >> 7) & 127, k = g & 127;
        out[g] = LDV(&v[(i + 1) * P2 + (j + 1) * P + (k + 1)]);
    }
    if (tid == 0) {
        out[NG]     = (float)it;
        out[NG + 1] = dv;
    }
}

extern "C" void kernel_launch(void* const* d_in, const int* in_sizes, int n_in,
                              void* d_out, int out_size, void* d_ws, size_t ws_size,
                              hipStream_t stream) {
    const float* img  = (const float*)d_in[0];
    const int*   sink = (const int*)d_in[2];   // sink_label (=3)
    float*       out  = (float*)d_out;

    char* ws = (char*)d_ws;
    size_t off = 0;
    float* v = (float*)(ws + off);
    off += (size_t)NPAD * sizeof(float);
    off = (off + 255) & ~(size_t)255;
    int* listB = (int*)(ws + off);
    off += (size_t)CAPC * sizeof(int);
    int* listR = (int*)(ws + off);
    off += (size_t)CAPC * sizeof(int);
    int* cntB = (int*)(ws + off);
    off += (size_t)NB * sizeof(int);
    int* cntR = (int*)(ws + off);
    off += (size_t)NB * sizeof(int);
    float* partB = (float*)(ws + off);
    off += (size_t)2 * NB * sizeof(float);
    float* partR = (float*)(ws + off);
    off += (size_t)2 * NB * sizeof(float);
    off = (off + 255) & ~(size_t)255;
    int* flags = (int*)(ws + off);
    off += (size_t)NB * sizeof(int);
    (void)ws_size; (void)in_sizes; (void)n_in; (void)out_size;

    void* args[] = { (void*)&img, (void*)&sink, (void*)&v,
                     (void*)&listB, (void*)&listR, (void*)&cntB, (void*)&cntR,
                     (void*)&partB, (void*)&partR, (void*)&flags, (void*)&out };
    hipLaunchCooperativeKernel((const void*)sor_kernel, dim3(NB), dim3(NT),
                               args, 0, stream);
}

// Round 5
// 9944.427 us; speedup vs baseline: 12.0785x; 1.1763x over previous
//
#include <hip/hip_runtime.h>
#include <hip/hip_cooperative_groups.h>

namespace cg = cooperative_groups;
typedef unsigned long long u64;

#define G    128
#define GG   (G * G)
#define P    130
#define P2   (P * P)
#define NPAD (P * P * P)        // 2,197,000
#define NG   (G * G * G)        // 2,097,152
#define NB   512
#define NT   256
#define TOT  (NB * NT)          // 131,072
#define CH   (NG / NB)          // 4096 cells per block
#define CT   (CH / NT)          // 16 cells per thread
#define CAPC (640 * 1024)
#define SAFEP (P2 + P + 1)      // harmless interior index for inactive slots

// device-scope (MALL-coherent, L1/L2-bypassing) accesses for all loop-shared data
__device__ inline float LDV(const float* p) {
    return __hip_atomic_load((float*)p, __ATOMIC_RELAXED, __HIP_MEMORY_SCOPE_AGENT);
}
__device__ inline void STV(float* p, float x) {
    __hip_atomic_store(p, x, __ATOMIC_RELAXED, __HIP_MEMORY_SCOPE_AGENT);
}
__device__ inline u64 LDF(const u64* p) {
    return __hip_atomic_load((u64*)p, __ATOMIC_RELAXED, __HIP_MEMORY_SCOPE_AGENT);
}

// block reduce: wave64 shuffle + 4-slot LDS combine (deterministic fixed order)
__device__ inline float bred(float x, int t, float* s4) {
    for (int o = 32; o; o >>= 1) x += __shfl_down(x, o, 64);
    __syncthreads();
    if ((t & 63) == 0) s4[t >> 6] = x;
    __syncthreads();
    return ((s4[0] + s4[1]) + s4[2]) + s4[3];
}

// payload-carrying fence-free barrier. flag = (phase<<32)|float_bits(partial),
// double-buffered by phase parity (slot reuse distance 2 -> no overwrite race).
// Wave 0 polls all NB flags with 8 loads IN FLIGHT per round (not serial) and
// returns the q-ordered payload sum per lane (t<64); identical in every block.
__device__ inline float gbar_pay(u64* fl, int phase, int b, int t, float part) {
    asm volatile("s_waitcnt vmcnt(0)" ::: "memory");  // drain this wave's stores
    __syncthreads();                                  // all waves drained
    if (t == 0) {
        u64 w = ((u64)(unsigned)phase << 32) | (u64)__float_as_uint(part);
        __hip_atomic_store(&fl[b], w, __ATOMIC_RELAXED, __HIP_MEMORY_SCOPE_AGENT);
    }
    float acc = 0.0f;
    if (t < 64) {
        u64 w0, w1, w2, w3, w4, w5, w6, w7;
        for (;;) {
            w0 = LDF(&fl[t      ]); w1 = LDF(&fl[t +  64]);
            w2 = LDF(&fl[t + 128]); w3 = LDF(&fl[t + 192]);
            w4 = LDF(&fl[t + 256]); w5 = LDF(&fl[t + 320]);
            w6 = LDF(&fl[t + 384]); w7 = LDF(&fl[t + 448]);
            if ((int)(w0 >> 32) >= phase && (int)(w1 >> 32) >= phase &&
                (int)(w2 >> 32) >= phase && (int)(w3 >> 32) >= phase &&
                (int)(w4 >> 32) >= phase && (int)(w5 >> 32) >= phase &&
                (int)(w6 >> 32) >= phase && (int)(w7 >> 32) >= phase) break;
            __builtin_amdgcn_s_sleep(1);
        }
        acc = __uint_as_float((unsigned)w0);
        acc = __fadd_rn(acc, __uint_as_float((unsigned)w1));
        acc = __fadd_rn(acc, __uint_as_float((unsigned)w2));
        acc = __fadd_rn(acc, __uint_as_float((unsigned)w3));
        acc = __fadd_rn(acc, __uint_as_float((unsigned)w4));
        acc = __fadd_rn(acc, __uint_as_float((unsigned)w5));
        acc = __fadd_rn(acc, __uint_as_float((unsigned)w6));
        acc = __fadd_rn(acc, __uint_as_float((unsigned)w7));
    }
    __syncthreads();
    return acc;
}

__global__ __launch_bounds__(NT, 4)
void sor_kernel(const float* __restrict__ img, const int* __restrict__ sinkp,
                float* __restrict__ v, int* __restrict__ listB, int* __restrict__ listR,
                int* __restrict__ cntB, int* __restrict__ cntR,
                u64* __restrict__ flags, float* __restrict__ out)
{
    cg::grid_group grid = cg::this_grid();
    const int t   = (int)threadIdx.x;
    const int b   = (int)blockIdx.x;
    const int tid = b * NT + t;
    const float wopt  = (float)(2.0 / (1.0 + 3.14159265358979323846 / 130.0));
    const float sinkf = (float)(*sinkp);

    __shared__ int   sB[NT], sR[NT];
    __shared__ float s4[4];
    __shared__ int   shN[4];   // baseB, baseR, nBtot, nRtot

    // reset both flag slots (ws not re-poisoned between replays); the cg
    // grid.sync()s below order every reset before any block's first gbar.
    if (t == 0) {
        __hip_atomic_store(&flags[b],      0ull, __ATOMIC_RELAXED, __HIP_MEMORY_SCOPE_AGENT);
        __hip_atomic_store(&flags[NB + b], 0ull, __ATOMIC_RELAXED, __HIP_MEMORY_SCOPE_AGENT);
    }

    // ---- init padded v: sink -> 1, else 0 ----
    for (int p = tid; p < NPAD; p += TOT) {
        int i = p / P2;
        int r = p - i * P2;
        int j = r / P;
        int k = r - j * P;
        float vv = 0.0f;
        if (i > 0 && i < P - 1 && j > 0 && j < P - 1 && k > 0 && k < P - 1) {
            float lab = img[(i - 1) * GG + (j - 1) * G + (k - 1)];
            vv = (lab == sinkf) ? 1.0f : 0.0f;
        }
        v[p] = vv;
    }

    // ---- per-thread active counts over contiguous 16-cell chunk ----
    const int g0 = b * CH + t * CT;
    int cB = 0, cR = 0;
    for (int q = 0; q < CT; ++q) {
        float lab = img[g0 + q];
        if (lab == 1.0f) {
            int g = g0 + q;
            int par = ((g >> 14) + ((g >> 7) & 127) + (g & 127)) & 1;
            if (par) cB++; else cR++;
        }
    }
    sB[t] = cB; sR[t] = cR;
    __syncthreads();
    for (int off = 1; off < NT; off <<= 1) {
        int aB = 0, aR = 0;
        if (t >= off) { aB = sB[t - off]; aR = sR[t - off]; }
        __syncthreads();
        if (t >= off) { sB[t] += aB; sR[t] += aR; }
        __syncthreads();
    }
    const int exB = sB[t] - cB;
    const int exR = sR[t] - cR;
    if (t == NT - 1) { cntB[b] = sB[t]; cntR[b] = sR[t]; }
    grid.sync();   // full fence: init v + counts + flag resets globally visible

    // ---- block base offsets + totals (redundant, deterministic) ----
    {
        int mB = 0, mR = 0, tB = 0, tR = 0;
        for (int e = t; e < NB; e += NT) {
            int vb = cntB[e], vr = cntR[e];
            tB += vb; tR += vr;
            if (e < b) { mB += vb; mR += vr; }
        }
        sB[t] = mB; sR[t] = mR;
        __syncthreads();
        for (int st = NT / 2; st > 0; st >>= 1) {
            if (t < st) { sB[t] += sB[t + st]; sR[t] += sR[t + st]; }
            __syncthreads();
        }
        if (t == 0) { shN[0] = sB[0]; shN[1] = sR[0]; }
        __syncthreads();
        sB[t] = tB; sR[t] = tR;
        __syncthreads();
        for (int st = NT / 2; st > 0; st >>= 1) {
            if (t < st) { sB[t] += sB[t + st]; sR[t] += sR[t + st]; }
            __syncthreads();
        }
        if (t == 0) { shN[2] = sB[0]; shN[3] = sR[0]; }
        __syncthreads();
    }
    const int baseB = shN[0], baseR = shN[1];
    const int nBt = shN[2], nRt = shN[3];

    // ---- write compacted lists (global cell order -> deterministic) ----
    {
        int pB = baseB + exB, pR = baseR + exR;
        for (int q = 0; q < CT; ++q) {
            int g = g0 + q;
            float lab = img[g];
            if (lab == 1.0f) {
                int i = g >> 14, j = (g >> 7) & 127, k = g & 127;
                int p = (i + 1) * P2 + (j + 1) * P + (k + 1);
                if ((i + j + k) & 1) listB[pB++] = p; else listR[pR++] = p;
            }
        }
    }
    grid.sync();   // full fence: lists visible + all caches clean of v
    // From here on, v is touched ONLY via bypass (agent-scope) ops.

    // ---- hoist cells into registers (3 slots/color + rare tail) ----
    int pb0 = (tid < nBt)           ? listB[tid]           : -1;
    int pb1 = (tid + TOT < nBt)     ? listB[tid + TOT]     : -1;
    int pb2 = (tid + 2 * TOT < nBt) ? listB[tid + 2 * TOT] : -1;
    int pr0 = (tid < nRt)           ? listR[tid]           : -1;
    int pr1 = (tid + TOT < nRt)     ? listR[tid + TOT]     : -1;
    int pr2 = (tid + 2 * TOT < nRt) ? listR[tid + 2 * TOT] : -1;

    // centers live in registers: active cells are gm (img==1), never sink,
    // so their initial v is exactly 0; only this thread ever writes them.
    float vb0 = 0.0f, vb1 = 0.0f, vb2 = 0.0f;
    float vr0 = 0.0f, vr1 = 0.0f, vr2 = 0.0f;

    // exact reference numerics per cell:
    // s = ((((v[+1]+v[-1])+v[+P])+v[-P])+v[+P2])+v[-P2]
    // adj = (wopt * (s - 6*v)) / 6 ; v += adj
#define CELL1(p, loc)                                                     \
    {                                                                     \
        float vc = LDV(&v[p]);                                            \
        float s = __fadd_rn(LDV(&v[(p) + 1]), LDV(&v[(p) - 1]));          \
        s = __fadd_rn(s, LDV(&v[(p) + P]));  s = __fadd_rn(s, LDV(&v[(p) - P]));   \
        s = __fadd_rn(s, LDV(&v[(p) + P2])); s = __fadd_rn(s, LDV(&v[(p) - P2]));  \
        float tt = __fsub_rn(s, __fmul_rn(6.0f, vc));                     \
        float adj = __fdiv_rn(__fmul_rn(wopt, tt), 6.0f);                 \
        STV(&v[p], __fadd_rn(vc, adj));                                   \
        loc += fabsf(adj);                                                \
    }

#define SWEEP3(c0, c1, c2, V0, V1, V2, LIST, NTOT, loc)                    \
    {                                                                      \
        const int q0 = (c0 >= 0) ? c0 : SAFEP;                             \
        const int q1 = (c1 >= 0) ? c1 : SAFEP;                             \
        const int q2 = (c2 >= 0) ? c2 : SAFEP;                             \
        float a1 = LDV(&v[q0 + 1]),  b1 = LDV(&v[q1 + 1]),  e1 = LDV(&v[q2 + 1]);  \
        float a2 = LDV(&v[q0 - 1]),  b2 = LDV(&v[q1 - 1]),  e2 = LDV(&v[q2 - 1]);  \
        float a3 = LDV(&v[q0 + P]),  b3 = LDV(&v[q1 + P]),  e3 = LDV(&v[q2 + P]);  \
        float a4 = LDV(&v[q0 - P]),  b4 = LDV(&v[q1 - P]),  e4 = LDV(&v[q2 - P]);  \
        float a5 = LDV(&v[q0 + P2]), b5 = LDV(&v[q1 + P2]), e5 = LDV(&v[q2 + P2]); \
        float a6 = LDV(&v[q0 - P2]), b6 = LDV(&v[q1 - P2]), e6 = LDV(&v[q2 - P2]); \
        float sa = __fadd_rn(a1, a2);                                      \
        sa = __fadd_rn(sa, a3); sa = __fadd_rn(sa, a4);                    \
        sa = __fadd_rn(sa, a5); sa = __fadd_rn(sa, a6);                    \
        float sb = __fadd_rn(b1, b2);                                      \
        sb = __fadd_rn(sb, b3); sb = __fadd_rn(sb, b4);                    \
        sb = __fadd_rn(sb, b5); sb = __fadd_rn(sb, b6);                    \
        float se = __fadd_rn(e1, e2);                                      \
        se = __fadd_rn(se, e3); se = __fadd_rn(se, e4);                    \
        se = __fadd_rn(se, e5); se = __fadd_rn(se, e6);                    \
        float ta = __fsub_rn(sa, __fmul_rn(6.0f, V0));                     \
        float tb = __fsub_rn(sb, __fmul_rn(6.0f, V1));                     \
        float te = __fsub_rn(se, __fmul_rn(6.0f, V2));                     \
        float adj0 = __fdiv_rn(__fmul_rn(wopt, ta), 6.0f);                 \
        float adj1 = __fdiv_rn(__fmul_rn(wopt, tb), 6.0f);                 \
        float adj2 = __fdiv_rn(__fmul_rn(wopt, te), 6.0f);                 \
        if (c0 >= 0) { V0 = __fadd_rn(V0, adj0); STV(&v[q0], V0); loc += fabsf(adj0); } \
        if (c1 >= 0) { V1 = __fadd_rn(V1, adj1); STV(&v[q1], V1); loc += fabsf(adj1); } \
        if (c2 >= 0) { V2 = __fadd_rn(V2, adj2); STV(&v[q2], V2); loc += fabsf(adj2); } \
        for (int x = tid + 3 * TOT; x < (NTOT); x += TOT) {                \
            const int p = LIST[x];                                         \
            CELL1(p, loc)                                                  \
        }                                                                  \
    }

    int it = 0;
    float dv = 0.0f;
    int phase = 0;
    do {
        // ---------- black ----------
        float locb = 0.0f;
        SWEEP3(pb0, pb1, pb2, vb0, vb1, vb2, listB, nBt, locb)
        float bs = bred(locb, t, s4);
        ++phase;
        float bacc = gbar_pay(flags + (size_t)(phase & 1) * NB, phase, b, t, bs);

        // ---------- red ----------
        float locr = 0.0f;
        SWEEP3(pr0, pr1, pr2, vr0, vr1, vr2, listR, nRt, locr)
        float rs = bred(locr, t, s4);
        ++phase;
        float racc = gbar_pay(flags + (size_t)(phase & 1) * NB, phase, b, t, rs);

        // ---------- dv: wave 0 reduces its harvested payloads, broadcast ----------
        if (t < 64) {
            float d = __fadd_rn(bacc, racc);
            for (int o = 32; o; o >>= 1) d += __shfl_down(d, o, 64);
            if (t == 0) s4[0] = d;
        }
        __syncthreads();
        dv = s4[0];          // bit-identical in every block (fixed order)

        ++it;
    } while (dv >= 0.05f && it <= 500);

    // ---- epilogue (v read via bypass: caches hold no valid v lines) ----
    for (int g = tid; g < NG; g += TOT) {
        int i = g >> 14, j = (g >> 7) & 127, k = g & 127;
        out[g] = LDV(&v[(i + 1) * P2 + (j + 1) * P + (k + 1)]);
    }
    if (tid == 0) {
        out[NG]     = (float)it;
        out[NG + 1] = dv;
    }
}

extern "C" void kernel_launch(void* const* d_in, const int* in_sizes, int n_in,
                              void* d_out, int out_size, void* d_ws, size_t ws_size,
                              hipStream_t stream) {
    const float* img  = (const float*)d_in[0];
    const int*   sink = (const int*)d_in[2];   // sink_label (=3)
    float*       out  = (float*)d_out;

    char* ws = (char*)d_ws;
    size_t off = 0;
    float* v = (float*)(ws + off);
    off += (size_t)NPAD * sizeof(float);
    off = (off + 255) & ~(size_t)255;
    int* listB = (int*)(ws + off);
    off += (size_t)CAPC * sizeof(int);
    int* listR = (int*)(ws + off);
    off += (size_t)CAPC * sizeof(int);
    int* cntB = (int*)(ws + off);
    off += (size_t)NB * sizeof(int);
    int* cntR = (int*)(ws + off);
    off += (size_t)NB * sizeof(int);
    off = (off + 255) & ~(size_t)255;
    u64* flags = (u64*)(ws + off);
    off += (size_t)2 * NB * sizeof(u64);
    (void)ws_size; (void)in_sizes; (void)n_in; (void)out_size;

    void* args[] = { (void*)&img, (void*)&sink, (void*)&v,
                     (void*)&listB, (void*)&listR, (void*)&cntB, (void*)&cntR,
                     (void*)&flags, (void*)&out };
    hipLaunchCooperativeKernel((const void*)sor_kernel, dim3(NB), dim3(NT),
                               args, 0, stream);
}

// Round 7
// 7625.331 us; speedup vs baseline: 15.7520x; 1.3041x over previous
//
#include <hip/hip_runtime.h>
#include <hip/hip_cooperative_groups.h>

namespace cg = cooperative_groups;
typedef unsigned long long u64;

#define G    128
#define GG   (G * G)
#define P    130
#define P2   (P * P)
#define NPAD (P * P * P)        // 2,197,000
#define NG   (G * G * G)        // 2,097,152
#define NB   512
#define NT   256
#define TOT  (NB * NT)          // 131,072
#define CH   (NG / NB)          // 4096 cells per block
#define CT   (CH / NT)          // 16 cells per thread
#define CAPC (640 * 1024)
#define SAFEP (P2 + P + 1)      // harmless interior index for inactive slots

// device-scope (MALL-coherent, L1/L2-bypassing) accesses for all loop-shared data
__device__ inline float LDV(const float* p) {
    return __hip_atomic_load((float*)p, __ATOMIC_RELAXED, __HIP_MEMORY_SCOPE_AGENT);
}
__device__ inline void STV(float* p, float x) {
    __hip_atomic_store(p, x, __ATOMIC_RELAXED, __HIP_MEMORY_SCOPE_AGENT);
}
__device__ inline u64 LDF(const u64* p) {
    return __hip_atomic_load((u64*)p, __ATOMIC_RELAXED, __HIP_MEMORY_SCOPE_AGENT);
}

// block reduce: wave64 shuffle + 4-slot LDS combine (deterministic fixed order)
__device__ inline float bred(float x, int t, float* s4) {
    for (int o = 32; o; o >>= 1) x += __shfl_down(x, o, 64);
    __syncthreads();
    if ((t & 63) == 0) s4[t >> 6] = x;
    __syncthreads();
    return ((s4[0] + s4[1]) + s4[2]) + s4[3];
}

// payload-carrying fence-free barrier. flag = (phase<<32)|float_bits(partial),
// double-buffered by phase parity. Wave 0 polls all NB flags 8-in-flight and
// returns the fixed-order payload sum per lane (t<64); identical in every block.
__device__ inline float gbar_pay(u64* fl, int phase, int b, int t, float part) {
    asm volatile("s_waitcnt vmcnt(0)" ::: "memory");  // drain this wave's stores
    __syncthreads();                                  // all waves drained
    if (t == 0) {
        u64 w = ((u64)(unsigned)phase << 32) | (u64)__float_as_uint(part);
        __hip_atomic_store(&fl[b], w, __ATOMIC_RELAXED, __HIP_MEMORY_SCOPE_AGENT);
    }
    float acc = 0.0f;
    if (t < 64) {
        u64 w0, w1, w2, w3, w4, w5, w6, w7;
        for (;;) {
            w0 = LDF(&fl[t      ]); w1 = LDF(&fl[t +  64]);
            w2 = LDF(&fl[t + 128]); w3 = LDF(&fl[t + 192]);
            w4 = LDF(&fl[t + 256]); w5 = LDF(&fl[t + 320]);
            w6 = LDF(&fl[t + 384]); w7 = LDF(&fl[t + 448]);
            if ((int)(w0 >> 32) >= phase && (int)(w1 >> 32) >= phase &&
                (int)(w2 >> 32) >= phase && (int)(w3 >> 32) >= phase &&
                (int)(w4 >> 32) >= phase && (int)(w5 >> 32) >= phase &&
                (int)(w6 >> 32) >= phase && (int)(w7 >> 32) >= phase) break;
            __builtin_amdgcn_s_sleep(1);
        }
        acc = __uint_as_float((unsigned)w0);
        acc = __fadd_rn(acc, __uint_as_float((unsigned)w1));
        acc = __fadd_rn(acc, __uint_as_float((unsigned)w2));
        acc = __fadd_rn(acc, __uint_as_float((unsigned)w3));
        acc = __fadd_rn(acc, __uint_as_float((unsigned)w4));
        acc = __fadd_rn(acc, __uint_as_float((unsigned)w5));
        acc = __fadd_rn(acc, __uint_as_float((unsigned)w6));
        acc = __fadd_rn(acc, __uint_as_float((unsigned)w7));
    }
    __syncthreads();
    return acc;
}

__global__ __launch_bounds__(NT, 4)
void sor_kernel(const float* __restrict__ img, const int* __restrict__ sinkp,
                float* __restrict__ v, int* __restrict__ listB, int* __restrict__ listR,
                int* __restrict__ cntB, int* __restrict__ cntR,
                u64* __restrict__ flags, float* __restrict__ out)
{
    cg::grid_group grid = cg::this_grid();
    const int t   = (int)threadIdx.x;
    const int b   = (int)blockIdx.x;
    const int tid = b * NT + t;
    const float wopt  = (float)(2.0 / (1.0 + 3.14159265358979323846 / 130.0));
    const float sinkf = (float)(*sinkp);

    __shared__ int   sB[NT], sR[NT];
    __shared__ float s4[4];
    __shared__ int   shN[4];   // baseB, baseR, nBtot, nRtot

    if (t == 0) {   // reset both flag slots; ordered by the cg grid.sync()s below
        __hip_atomic_store(&flags[b],      0ull, __ATOMIC_RELAXED, __HIP_MEMORY_SCOPE_AGENT);
        __hip_atomic_store(&flags[NB + b], 0ull, __ATOMIC_RELAXED, __HIP_MEMORY_SCOPE_AGENT);
    }

    // ---- init padded v: sink -> 1, else 0 ----
    for (int p = tid; p < NPAD; p += TOT) {
        int i = p / P2;
        int r = p - i * P2;
        int j = r / P;
        int k = r - j * P;
        float vv = 0.0f;
        if (i > 0 && i < P - 1 && j > 0 && j < P - 1 && k > 0 && k < P - 1) {
            float lab = img[(i - 1) * GG + (j - 1) * G + (k - 1)];
            vv = (lab == sinkf) ? 1.0f : 0.0f;
        }
        v[p] = vv;
    }

    // ---- per-thread active counts over contiguous 16-cell chunk ----
    const int g0 = b * CH + t * CT;
    int cB = 0, cR = 0;
    for (int q = 0; q < CT; ++q) {
        float lab = img[g0 + q];
        if (lab == 1.0f) {
            int g = g0 + q;
            int par = ((g >> 14) + ((g >> 7) & 127) + (g & 127)) & 1;
            if (par) cB++; else cR++;
        }
    }
    sB[t] = cB; sR[t] = cR;
    __syncthreads();
    for (int off = 1; off < NT; off <<= 1) {
        int aB = 0, aR = 0;
        if (t >= off) { aB = sB[t - off]; aR = sR[t - off]; }
        __syncthreads();
        if (t >= off) { sB[t] += aB; sR[t] += aR; }
        __syncthreads();
    }
    const int exB = sB[t] - cB;
    const int exR = sR[t] - cR;
    if (t == NT - 1) { cntB[b] = sB[t]; cntR[b] = sR[t]; }
    grid.sync();   // full fence: init v + counts + flag resets globally visible

    // ---- block base offsets + totals (redundant, deterministic) ----
    {
        int mB = 0, mR = 0, tB = 0, tR = 0;
        for (int e = t; e < NB; e += NT) {
            int vb = cntB[e], vr = cntR[e];
            tB += vb; tR += vr;
            if (e < b) { mB += vb; mR += vr; }
        }
        sB[t] = mB; sR[t] = mR;
        __syncthreads();
        for (int st = NT / 2; st > 0; st >>= 1) {
            if (t < st) { sB[t] += sB[t + st]; sR[t] += sR[t + st]; }
            __syncthreads();
        }
        if (t == 0) { shN[0] = sB[0]; shN[1] = sR[0]; }
        __syncthreads();
        sB[t] = tB; sR[t] = tR;
        __syncthreads();
        for (int st = NT / 2; st > 0; st >>= 1) {
            if (t < st) { sB[t] += sB[t + st]; sR[t] += sR[t + st]; }
            __syncthreads();
        }
        if (t == 0) { shN[2] = sB[0]; shN[3] = sR[0]; }
        __syncthreads();
    }
    const int baseB = shN[0], baseR = shN[1];
    const int nBt = shN[2], nRt = shN[3];

    // ---- write compacted lists (global cell order -> deterministic) ----
    {
        int pB = baseB + exB, pR = baseR + exR;
        for (int q = 0; q < CT; ++q) {
            int g = g0 + q;
            float lab = img[g];
            if (lab == 1.0f) {
                int i = g >> 14, j = (g >> 7) & 127, k = g & 127;
                int p = (i + 1) * P2 + (j + 1) * P + (k + 1);
                if ((i + j + k) & 1) listB[pB++] = p; else listR[pR++] = p;
            }
        }
    }
    grid.sync();   // full fence: lists visible + all caches clean of v
    // From here on, v is touched ONLY via bypass (agent-scope) ops.

    // ---- hoist cells: static/dynamic neighbor split, all in registers ----
    // Non-gm neighbors (bg/src=0, sink=1, pad=0) are frozen -> precompute sum.
    // Gm neighbors (opposite color, avg 1.5 of 6) are the only dynamic loads.
#define HOIST(LIST, NTOT, X, PV, NDV, SSV, D0, D1, D2, D3, D4, D5)          \
    {                                                                       \
        PV = -1; NDV = 0; SSV = 0.0f;                                       \
        D0 = SAFEP; D1 = SAFEP; D2 = SAFEP; D3 = SAFEP; D4 = SAFEP; D5 = SAFEP; \
        if ((X) < (NTOT)) {                                                 \
            const int p = LIST[X]; PV = p;                                  \
            const int pi = p / P2; const int rr = p - pi * P2;              \
            const int pj = rr / P; const int pk = rr - pj * P;              \
            const int i = pi - 1, j = pj - 1, k = pk - 1;                   \
            float ss = 0.0f; int nd = 0; int dd[6];                         \
            dd[0] = SAFEP; dd[1] = SAFEP; dd[2] = SAFEP;                    \
            dd[3] = SAFEP; dd[4] = SAFEP; dd[5] = SAFEP;                    \
            if (k + 1 <= G - 1) { float lb = img[i * GG + j * G + (k + 1)]; \
                if (lb == 1.0f) dd[nd++] = p + 1;                           \
                else ss = __fadd_rn(ss, (lb == sinkf) ? 1.0f : 0.0f); }     \
            if (k - 1 >= 0)     { float lb = img[i * GG + j * G + (k - 1)]; \
                if (lb == 1.0f) dd[nd++] = p - 1;                           \
                else ss = __fadd_rn(ss, (lb == sinkf) ? 1.0f : 0.0f); }     \
            if (j + 1 <= G - 1) { float lb = img[i * GG + (j + 1) * G + k]; \
                if (lb == 1.0f) dd[nd++] = p + P;                           \
                else ss = __fadd_rn(ss, (lb == sinkf) ? 1.0f : 0.0f); }     \
            if (j - 1 >= 0)     { float lb = img[i * GG + (j - 1) * G + k]; \
                if (lb == 1.0f) dd[nd++] = p - P;                           \
                else ss = __fadd_rn(ss, (lb == sinkf) ? 1.0f : 0.0f); }     \
            if (i + 1 <= G - 1) { float lb = img[(i + 1) * GG + j * G + k]; \
                if (lb == 1.0f) dd[nd++] = p + P2;                          \
                else ss = __fadd_rn(ss, (lb == sinkf) ? 1.0f : 0.0f); }     \
            if (i - 1 >= 0)     { float lb = img[(i - 1) * GG + j * G + k]; \
                if (lb == 1.0f) dd[nd++] = p - P2;                          \
                else ss = __fadd_rn(ss, (lb == sinkf) ? 1.0f : 0.0f); }     \
            NDV = nd; SSV = ss;                                             \
            D0 = dd[0]; D1 = dd[1]; D2 = dd[2];                             \
            D3 = dd[3]; D4 = dd[4]; D5 = dd[5];                             \
        }                                                                   \
    }

    int pB0, ndB0, dB00, dB01, dB02, dB03, dB04, dB05; float ssB0;
    int pB1, ndB1, dB10, dB11, dB12, dB13, dB14, dB15; float ssB1;
    int pR0, ndR0, dR00, dR01, dR02, dR03, dR04, dR05; float ssR0;
    int pR1, ndR1, dR10, dR11, dR12, dR13, dR14, dR15; float ssR1;
    HOIST(listB, nBt, tid,       pB0, ndB0, ssB0, dB00, dB01, dB02, dB03, dB04, dB05)
    HOIST(listB, nBt, tid + TOT, pB1, ndB1, ssB1, dB10, dB11, dB12, dB13, dB14, dB15)
    HOIST(listR, nRt, tid,       pR0, ndR0, ssR0, dR00, dR01, dR02, dR03, dR04, dR05)
    HOIST(listR, nRt, tid + TOT, pR1, ndR1, ssR1, dR10, dR11, dR12, dR13, dR14, dR15)

    // centers in registers: gm cells start at exactly 0; only this thread writes.
    float vB0 = 0.0f, vB1 = 0.0f, vR0 = 0.0f, vR1 = 0.0f;

#define CELL1(p, loc)                                                     \
    {                                                                     \
        float vc = LDV(&v[p]);                                            \
        float s = __fadd_rn(LDV(&v[(p) + 1]), LDV(&v[(p) - 1]));          \
        s = __fadd_rn(s, LDV(&v[(p) + P]));  s = __fadd_rn(s, LDV(&v[(p) - P]));   \
        s = __fadd_rn(s, LDV(&v[(p) + P2])); s = __fadd_rn(s, LDV(&v[(p) - P2]));  \
        float tt = __fsub_rn(s, __fmul_rn(6.0f, vc));                     \
        float adj = __fdiv_rn(__fmul_rn(wopt, tt), 6.0f);                 \
        STV(&v[p], __fadd_rn(vc, adj));                                   \
        loc = __fadd_rn(loc, fabsf(adj));                                 \
    }

    // two slots; all dynamic loads issued before any arithmetic (MLP).
    // inactive slot (nd=0, ss=0, v=0) computes adj==0 exactly -> no dv pollution.
#define SLOT_SWEEP2(ND0, SS0, V0, PP0, A0, A1, A2, A3, A4, A5,             \
                    ND1, SS1, V1, PP1, B0, B1, B2, B3, B4, B5, loc)        \
    {                                                                      \
        float x00 = (0 < ND0) ? LDV(&v[A0]) : 0.0f;                        \
        float x01 = (1 < ND0) ? LDV(&v[A1]) : 0.0f;                        \
        float x02 = (2 < ND0) ? LDV(&v[A2]) : 0.0f;                        \
        float x03 = (3 < ND0) ? LDV(&v[A3]) : 0.0f;                        \
        float x04 = (4 < ND0) ? LDV(&v[A4]) : 0.0f;                        \
        float x05 = (5 < ND0) ? LDV(&v[A5]) : 0.0f;                        \
        float x10 = (0 < ND1) ? LDV(&v[B0]) : 0.0f;                        \
        float x11 = (1 < ND1) ? LDV(&v[B1]) : 0.0f;                        \
        float x12 = (2 < ND1) ? LDV(&v[B2]) : 0.0f;                        \
        float x13 = (3 < ND1) ? LDV(&v[B3]) : 0.0f;                        \
        float x14 = (4 < ND1) ? LDV(&v[B4]) : 0.0f;                        \
        float x15 = (5 < ND1) ? LDV(&v[B5]) : 0.0f;                        \
        float s0 = __fadd_rn(x00, x01);                                    \
        s0 = __fadd_rn(s0, x02); s0 = __fadd_rn(s0, x03);                  \
        s0 = __fadd_rn(s0, x04); s0 = __fadd_rn(s0, x05);                  \
        s0 = __fadd_rn(s0, SS0);                                           \
        float s1 = __fadd_rn(x10, x11);                                    \
        s1 = __fadd_rn(s1, x12); s1 = __fadd_rn(s1, x13);                  \
        s1 = __fadd_rn(s1, x14); s1 = __fadd_rn(s1, x15);                  \
        s1 = __fadd_rn(s1, SS1);                                           \
        float t0 = __fsub_rn(s0, __fmul_rn(6.0f, V0));                     \
        float t1 = __fsub_rn(s1, __fmul_rn(6.0f, V1));                     \
        float adj0 = __fdiv_rn(__fmul_rn(wopt, t0), 6.0f);                 \
        float adj1 = __fdiv_rn(__fmul_rn(wopt, t1), 6.0f);                 \
        V0 = __fadd_rn(V0, adj0);                                          \
        V1 = __fadd_rn(V1, adj1);                                          \
        if (ND0 > 0) STV(&v[PP0], V0);                                     \
        if (ND1 > 0) STV(&v[PP1], V1);                                     \
        loc = __fadd_rn(loc, fabsf(adj0));                                 \
        loc = __fadd_rn(loc, fabsf(adj1));                                 \
    }

    int it = 0;
    float dv = 0.0f;
    int phase = 0;
    do {
        // ---------- black ----------
        float locb = 0.0f;
        SLOT_SWEEP2(ndB0, ssB0, vB0, pB0, dB00, dB01, dB02, dB03, dB04, dB05,
                    ndB1, ssB1, vB1, pB1, dB10, dB11, dB12, dB13, dB14, dB15, locb)
        for (int x = tid + 2 * TOT; x < nBt; x += TOT) {
            const int p = listB[x];
            CELL1(p, locb)
        }
        float bs = bred(locb, t, s4);
        ++phase;
        float bacc = gbar_pay(flags + (size_t)(phase & 1) * NB, phase, b, t, bs);

        // ---------- red ----------
        float locr = 0.0f;
        SLOT_SWEEP2(ndR0, ssR0, vR0, pR0, dR00, dR01, dR02, dR03, dR04, dR05,
                    ndR1, ssR1, vR1, pR1, dR10, dR11, dR12, dR13, dR14, dR15, locr)
        for (int x = tid + 2 * TOT; x < nRt; x += TOT) {
            const int p = listR[x];
            CELL1(p, locr)
        }
        float rs = bred(locr, t, s4);
        ++phase;
        float racc = gbar_pay(flags + (size_t)(phase & 1) * NB, phase, b, t, rs);

        // ---------- dv: wave 0 reduces harvested payloads, broadcast ----------
        if (t < 64) {
            float d = __fadd_rn(bacc, racc);
            for (int o = 32; o; o >>= 1) d += __shfl_down(d, o, 64);
            if (t == 0) s4[0] = d;
        }
        __syncthreads();
        dv = s4[0];          // bit-identical in every block (fixed order)

        ++it;
    } while (dv >= 0.05f && it <= 500);

    // reader-less cells (nd==0) were never stored in the loop: store once now,
    // then one more barrier so every block sees all final values.
    if (pB0 >= 0 && ndB0 == 0) STV(&v[pB0], vB0);
    if (pB1 >= 0 && ndB1 == 0) STV(&v[pB1], vB1);
    if (pR0 >= 0 && ndR0 == 0) STV(&v[pR0], vR0);
    if (pR1 >= 0 && ndR1 == 0) STV(&v[pR1], vR1);
    ++phase;
    gbar_pay(flags + (size_t)(phase & 1) * NB, phase, b, t, 0.0f);

    // ---- epilogue (v read via bypass: caches hold no valid v lines) ----
    for (int g = tid; g < NG; g += TOT) {
        int i = g >> 14, j = (g >> 7) & 127, k = g & 127;
        out[g] = LDV(&v[(i + 1) * P2 + (j + 1) * P + (k + 1)]);
    }
    if (tid == 0) {
        out[NG]     = (float)it;
        out[NG + 1] = dv;
    }
}

extern "C" void kernel_launch(void* const* d_in, const int* in_sizes, int n_in,
                              void* d_out, int out_size, void* d_ws, size_t ws_size,
                              hipStream_t stream) {
    const float* img  = (const float*)d_in[0];
    const int*   sink = (const int*)d_in[2];   // sink_label (=3)
    float*       out  = (float*)d_out;

    char* ws = (char*)d_ws;
    size_t off = 0;
    float* v = (float*)(ws + off);
    off += (size_t)NPAD * sizeof(float);
    off = (off + 255) & ~(size_t)255;
    int* listB = (int*)(ws + off);
    off += (size_t)CAPC * sizeof(int);
    int* listR = (int*)(ws + off);
    off += (size_t)CAPC * sizeof(int);
    int* cntB = (int*)(ws + off);
    off += (size_t)NB * sizeof(int);
    int* cntR = (int*)(ws + off);
    off += (size_t)NB * sizeof(int);
    off = (off + 255) & ~(size_t)255;
    u64* flags = (u64*)(ws + off);
    off += (size_t)2 * NB * sizeof(u64);
    (void)ws_size; (void)in_sizes; (void)n_in; (void)out_size;

    void* args[] = { (void*)&img, (void*)&sink, (void*)&v,
                     (void*)&listB, (void*)&listR, (void*)&cntB, (void*)&cntR,
                     (void*)&flags, (void*)&out };
    hipLaunchCooperativeKernel((const void*)sor_kernel, dim3(NB), dim3(NT),
                               args, 0, stream);
}

// Round 8
// 5389.814 us; speedup vs baseline: 22.2854x; 1.4148x over previous
//
#include <hip/hip_runtime.h>
#include <hip/hip_cooperative_groups.h>

namespace cg = cooperative_groups;
typedef unsigned long long u64;

#define G    128
#define GG   (G * G)
#define P    130
#define P2   (P * P)
#define NPAD (P * P * P)        // 2,197,000
#define NG   (G * G * G)        // 2,097,152
#define NB   512
#define NT   256
#define TOT  (NB * NT)          // 131,072
#define CH   (NG / NB)          // 4096 cells per block
#define CT   (CH / NT)          // 16 cells per thread
#define CAPC (640 * 1024)
#define SAFEP (P2 + P + 1)      // harmless interior index for inactive slots
#define NLEAD 8
#define NCH   (NB / NLEAD)      // 64 children per leader

// device-scope (MALL-coherent, L1/L2-bypassing) accesses for all loop-shared data
__device__ inline float LDV(const float* p) {
    return __hip_atomic_load((float*)p, __ATOMIC_RELAXED, __HIP_MEMORY_SCOPE_AGENT);
}
__device__ inline void STV(float* p, float x) {
    __hip_atomic_store(p, x, __ATOMIC_RELAXED, __HIP_MEMORY_SCOPE_AGENT);
}
__device__ inline u64 LDF(const u64* p) {
    return __hip_atomic_load((u64*)p, __ATOMIC_RELAXED, __HIP_MEMORY_SCOPE_AGENT);
}

// block reduce: wave64 shuffle + 4-slot LDS combine (deterministic fixed order)
__device__ inline float bred(float x, int t, float* s4) {
    for (int o = 32; o; o >>= 1) x += __shfl_down(x, o, 64);
    __syncthreads();
    if ((t & 63) == 0) s4[t >> 6] = x;
    __syncthreads();
    return ((s4[0] + s4[1]) + s4[2]) + s4[3];
}

// two-level payload barrier. leaf flag = (phase<<32)|bits(blockPartial), slot by
// phase parity (reuse distance 2; strict because every block is some leader's
// child). Leaders (b<8) poll their 64 children 1-load/lane, shfl-tree-sum the
// payloads (fixed order -> deterministic), publish (phase, childSum) to leader
// flag. All blocks then poll the 8 leader flags (one 64B line per round) and
// return the fixed-order 8-leader sum == the global sum; identical everywhere.
__device__ inline float gbar2(u64* __restrict__ leaf, u64* __restrict__ lead,
                              int phase, int b, int t, float part) {
    asm volatile("s_waitcnt vmcnt(0)" ::: "memory");  // drain this wave's stores
    __syncthreads();                                  // all waves drained
    const int slot = phase & 1;
    if (t == 0) {
        u64 w = ((u64)(unsigned)phase << 32) | (u64)__float_as_uint(part);
        __hip_atomic_store(&leaf[slot * NB + b], w, __ATOMIC_RELAXED,
                           __HIP_MEMORY_SCOPE_AGENT);
    }
    float lsum = 0.0f;
    if (t < 64) {
        if (b < NLEAD) {
            const u64* lp = &leaf[slot * NB + b * NCH + t];  // 1 child per lane
            u64 w;
            for (;;) {
                w = LDF(lp);
                if ((int)(w >> 32) >= phase) break;
                __builtin_amdgcn_s_sleep(1);
            }
            float x = __uint_as_float((unsigned)w);
            for (int o = 32; o; o >>= 1) x = __fadd_rn(x, __shfl_down(x, o, 64));
            if (t == 0) {
                u64 lw = ((u64)(unsigned)phase << 32) | (u64)__float_as_uint(x);
                __hip_atomic_store(&lead[slot * NLEAD + b], lw, __ATOMIC_RELAXED,
                                   __HIP_MEMORY_SCOPE_AGENT);
            }
        }
        const u64* gp = &lead[slot * NLEAD + (t & 7)];   // 8 flags, one 64B line
        u64 w;
        for (;;) {
            w = LDF(gp);
            if (__all((int)(w >> 32) >= phase)) break;
            __builtin_amdgcn_s_sleep(1);
        }
        float pay = __uint_as_float((unsigned)w);
        lsum = __shfl(pay, 0, 64);
        lsum = __fadd_rn(lsum, __shfl(pay, 1, 64));
        lsum = __fadd_rn(lsum, __shfl(pay, 2, 64));
        lsum = __fadd_rn(lsum, __shfl(pay, 3, 64));
        lsum = __fadd_rn(lsum, __shfl(pay, 4, 64));
        lsum = __fadd_rn(lsum, __shfl(pay, 5, 64));
        lsum = __fadd_rn(lsum, __shfl(pay, 6, 64));
        lsum = __fadd_rn(lsum, __shfl(pay, 7, 64));
    }
    __syncthreads();
    return lsum;   // global color-sum, valid for t<64, identical in every block
}

__global__ __launch_bounds__(NT, 4)
void sor_kernel(const float* __restrict__ img, const int* __restrict__ sinkp,
                float* __restrict__ v, int* __restrict__ listB, int* __restrict__ listR,
                int* __restrict__ cntB, int* __restrict__ cntR,
                u64* __restrict__ leaf, u64* __restrict__ lead,
                float* __restrict__ out)
{
    cg::grid_group grid = cg::this_grid();
    const int t   = (int)threadIdx.x;
    const int b   = (int)blockIdx.x;
    const int tid = b * NT + t;
    const float wopt  = (float)(2.0 / (1.0 + 3.14159265358979323846 / 130.0));
    const float sinkf = (float)(*sinkp);

    __shared__ int   sB[NT], sR[NT];
    __shared__ float s4[4];
    __shared__ int   shN[4];   // baseB, baseR, nBtot, nRtot

    if (t == 0) {   // reset flag slots; ordered by the cg grid.sync()s below
        __hip_atomic_store(&leaf[b],      0ull, __ATOMIC_RELAXED, __HIP_MEMORY_SCOPE_AGENT);
        __hip_atomic_store(&leaf[NB + b], 0ull, __ATOMIC_RELAXED, __HIP_MEMORY_SCOPE_AGENT);
        if (b < NLEAD) {
            __hip_atomic_store(&lead[b],         0ull, __ATOMIC_RELAXED, __HIP_MEMORY_SCOPE_AGENT);
            __hip_atomic_store(&lead[NLEAD + b], 0ull, __ATOMIC_RELAXED, __HIP_MEMORY_SCOPE_AGENT);
        }
    }

    // ---- init padded v: sink -> 1, else 0 ----
    for (int p = tid; p < NPAD; p += TOT) {
        int i = p / P2;
        int r = p - i * P2;
        int j = r / P;
        int k = r - j * P;
        float vv = 0.0f;
        if (i > 0 && i < P - 1 && j > 0 && j < P - 1 && k > 0 && k < P - 1) {
            float lab = img[(i - 1) * GG + (j - 1) * G + (k - 1)];
            vv = (lab == sinkf) ? 1.0f : 0.0f;
        }
        v[p] = vv;
    }

    // ---- per-thread active counts over contiguous 16-cell chunk ----
    const int g0 = b * CH + t * CT;
    int cB = 0, cR = 0;
    for (int q = 0; q < CT; ++q) {
        float lab = img[g0 + q];
        if (lab == 1.0f) {
            int g = g0 + q;
            int par = ((g >> 14) + ((g >> 7) & 127) + (g & 127)) & 1;
            if (par) cB++; else cR++;
        }
    }
    sB[t] = cB; sR[t] = cR;
    __syncthreads();
    for (int off = 1; off < NT; off <<= 1) {
        int aB = 0, aR = 0;
        if (t >= off) { aB = sB[t - off]; aR = sR[t - off]; }
        __syncthreads();
        if (t >= off) { sB[t] += aB; sR[t] += aR; }
        __syncthreads();
    }
    const int exB = sB[t] - cB;
    const int exR = sR[t] - cR;
    if (t == NT - 1) { cntB[b] = sB[t]; cntR[b] = sR[t]; }
    grid.sync();   // full fence: init v + counts + flag resets globally visible

    // ---- block base offsets + totals (redundant, deterministic) ----
    {
        int mB = 0, mR = 0, tB = 0, tR = 0;
        for (int e = t; e < NB; e += NT) {
            int vb = cntB[e], vr = cntR[e];
            tB += vb; tR += vr;
            if (e < b) { mB += vb; mR += vr; }
        }
        sB[t] = mB; sR[t] = mR;
        __syncthreads();
        for (int st = NT / 2; st > 0; st >>= 1) {
            if (t < st) { sB[t] += sB[t + st]; sR[t] += sR[t + st]; }
            __syncthreads();
        }
        if (t == 0) { shN[0] = sB[0]; shN[1] = sR[0]; }
        __syncthreads();
        sB[t] = tB; sR[t] = tR;
        __syncthreads();
        for (int st = NT / 2; st > 0; st >>= 1) {
            if (t < st) { sB[t] += sB[t + st]; sR[t] += sR[t + st]; }
            __syncthreads();
        }
        if (t == 0) { shN[2] = sB[0]; shN[3] = sR[0]; }
        __syncthreads();
    }
    const int baseB = shN[0], baseR = shN[1];
    const int nBt = shN[2], nRt = shN[3];

    // ---- write compacted lists (global cell order -> deterministic) ----
    {
        int pB = baseB + exB, pR = baseR + exR;
        for (int q = 0; q < CT; ++q) {
            int g = g0 + q;
            float lab = img[g];
            if (lab == 1.0f) {
                int i = g >> 14, j = (g >> 7) & 127, k = g & 127;
                int p = (i + 1) * P2 + (j + 1) * P + (k + 1);
                if ((i + j + k) & 1) listB[pB++] = p; else listR[pR++] = p;
            }
        }
    }
    grid.sync();   // full fence: lists visible + all caches clean of v
    // From here on, v is touched ONLY via bypass (agent-scope) ops.

    // ---- hoist cells: static/dynamic neighbor split, all in registers ----
#define HOIST(LIST, NTOT, X, PV, NDV, SSV, D0, D1, D2, D3, D4, D5)          \
    {                                                                       \
        PV = -1; NDV = 0; SSV = 0.0f;                                       \
        D0 = SAFEP; D1 = SAFEP; D2 = SAFEP; D3 = SAFEP; D4 = SAFEP; D5 = SAFEP; \
        if ((X) < (NTOT)) {                                                 \
            const int p = LIST[X]; PV = p;                                  \
            const int pi = p / P2; const int rr = p - pi * P2;              \
            const int pj = rr / P; const int pk = rr - pj * P;              \
            const int i = pi - 1, j = pj - 1, k = pk - 1;                   \
            float ss = 0.0f; int nd = 0; int dd[6];                         \
            dd[0] = SAFEP; dd[1] = SAFEP; dd[2] = SAFEP;                    \
            dd[3] = SAFEP; dd[4] = SAFEP; dd[5] = SAFEP;                    \
            if (k + 1 <= G - 1) { float lb = img[i * GG + j * G + (k + 1)]; \
                if (lb == 1.0f) dd[nd++] = p + 1;                           \
                else ss = __fadd_rn(ss, (lb == sinkf) ? 1.0f : 0.0f); }     \
            if (k - 1 >= 0)     { float lb = img[i * GG + j * G + (k - 1)]; \
                if (lb == 1.0f) dd[nd++] = p - 1;                           \
                else ss = __fadd_rn(ss, (lb == sinkf) ? 1.0f : 0.0f); }     \
            if (j + 1 <= G - 1) { float lb = img[i * GG + (j + 1) * G + k]; \
                if (lb == 1.0f) dd[nd++] = p + P;                           \
                else ss = __fadd_rn(ss, (lb == sinkf) ? 1.0f : 0.0f); }     \
            if (j - 1 >= 0)     { float lb = img[i * GG + (j - 1) * G + k]; \
                if (lb == 1.0f) dd[nd++] = p - P;                           \
                else ss = __fadd_rn(ss, (lb == sinkf) ? 1.0f : 0.0f); }     \
            if (i + 1 <= G - 1) { float lb = img[(i + 1) * GG + j * G + k]; \
                if (lb == 1.0f) dd[nd++] = p + P2;                          \
                else ss = __fadd_rn(ss, (lb == sinkf) ? 1.0f : 0.0f); }     \
            if (i - 1 >= 0)     { float lb = img[(i - 1) * GG + j * G + k]; \
                if (lb == 1.0f) dd[nd++] = p - P2;                          \
                else ss = __fadd_rn(ss, (lb == sinkf) ? 1.0f : 0.0f); }     \
            NDV = nd; SSV = ss;                                             \
            D0 = dd[0]; D1 = dd[1]; D2 = dd[2];                             \
            D3 = dd[3]; D4 = dd[4]; D5 = dd[5];                             \
        }                                                                   \
    }

    int pB0, ndB0, dB00, dB01, dB02, dB03, dB04, dB05; float ssB0;
    int pB1, ndB1, dB10, dB11, dB12, dB13, dB14, dB15; float ssB1;
    int pR0, ndR0, dR00, dR01, dR02, dR03, dR04, dR05; float ssR0;
    int pR1, ndR1, dR10, dR11, dR12, dR13, dR14, dR15; float ssR1;
    HOIST(listB, nBt, tid,       pB0, ndB0, ssB0, dB00, dB01, dB02, dB03, dB04, dB05)
    HOIST(listB, nBt, tid + TOT, pB1, ndB1, ssB1, dB10, dB11, dB12, dB13, dB14, dB15)
    HOIST(listR, nRt, tid,       pR0, ndR0, ssR0, dR00, dR01, dR02, dR03, dR04, dR05)
    HOIST(listR, nRt, tid + TOT, pR1, ndR1, ssR1, dR10, dR11, dR12, dR13, dR14, dR15)

    // centers in registers: gm cells start at exactly 0; only this thread writes.
    float vB0 = 0.0f, vB1 = 0.0f, vR0 = 0.0f, vR1 = 0.0f;

#define CELL1(p, loc)                                                     \
    {                                                                     \
        float vc = LDV(&v[p]);                                            \
        float s = __fadd_rn(LDV(&v[(p) + 1]), LDV(&v[(p) - 1]));          \
        s = __fadd_rn(s, LDV(&v[(p) + P]));  s = __fadd_rn(s, LDV(&v[(p) - P]));   \
        s = __fadd_rn(s, LDV(&v[(p) + P2])); s = __fadd_rn(s, LDV(&v[(p) - P2]));  \
        float tt = __fsub_rn(s, __fmul_rn(6.0f, vc));                     \
        float adj = __fdiv_rn(__fmul_rn(wopt, tt), 6.0f);                 \
        STV(&v[p], __fadd_rn(vc, adj));                                   \
        loc = __fadd_rn(loc, fabsf(adj));                                 \
    }

#define SLOT_SWEEP2(ND0, SS0, V0, PP0, A0, A1, A2, A3, A4, A5,             \
                    ND1, SS1, V1, PP1, B0, B1, B2, B3, B4, B5, loc)        \
    {                                                                      \
        float x00 = (0 < ND0) ? LDV(&v[A0]) : 0.0f;                        \
        float x01 = (1 < ND0) ? LDV(&v[A1]) : 0.0f;                        \
        float x02 = (2 < ND0) ? LDV(&v[A2]) : 0.0f;                        \
        float x03 = (3 < ND0) ? LDV(&v[A3]) : 0.0f;                        \
        float x04 = (4 < ND0) ? LDV(&v[A4]) : 0.0f;                        \
        float x05 = (5 < ND0) ? LDV(&v[A5]) : 0.0f;                        \
        float x10 = (0 < ND1) ? LDV(&v[B0]) : 0.0f;                        \
        float x11 = (1 < ND1) ? LDV(&v[B1]) : 0.0f;                        \
        float x12 = (2 < ND1) ? LDV(&v[B2]) : 0.0f;                        \
        float x13 = (3 < ND1) ? LDV(&v[B3]) : 0.0f;                        \
        float x14 = (4 < ND1) ? LDV(&v[B4]) : 0.0f;                        \
        float x15 = (5 < ND1) ? LDV(&v[B5]) : 0.0f;                        \
        float s0 = __fadd_rn(x00, x01);                                    \
        s0 = __fadd_rn(s0, x02); s0 = __fadd_rn(s0, x03);                  \
        s0 = __fadd_rn(s0, x04); s0 = __fadd_rn(s0, x05);                  \
        s0 = __fadd_rn(s0, SS0);                                           \
        float s1 = __fadd_rn(x10, x11);                                    \
        s1 = __fadd_rn(s1, x12); s1 = __fadd_rn(s1, x13);                  \
        s1 = __fadd_rn(s1, x14); s1 = __fadd_rn(s1, x15);                  \
        s1 = __fadd_rn(s1, SS1);                                           \
        float t0 = __fsub_rn(s0, __fmul_rn(6.0f, V0));                     \
        float t1 = __fsub_rn(s1, __fmul_rn(6.0f, V1));                     \
        float adj0 = __fdiv_rn(__fmul_rn(wopt, t0), 6.0f);                 \
        float adj1 = __fdiv_rn(__fmul_rn(wopt, t1), 6.0f);                 \
        V0 = __fadd_rn(V0, adj0);                                          \
        V1 = __fadd_rn(V1, adj1);                                          \
        if (ND0 > 0) STV(&v[PP0], V0);                                     \
        if (ND1 > 0) STV(&v[PP1], V1);                                     \
        loc = __fadd_rn(loc, fabsf(adj0));                                 \
        loc = __fadd_rn(loc, fabsf(adj1));                                 \
    }

    int it = 0;
    float dv = 0.0f;
    int phase = 0;
    do {
        // ---------- black ----------
        float locb = 0.0f;
        SLOT_SWEEP2(ndB0, ssB0, vB0, pB0, dB00, dB01, dB02, dB03, dB04, dB05,
                    ndB1, ssB1, vB1, pB1, dB10, dB11, dB12, dB13, dB14, dB15, locb)
        for (int x = tid + 2 * TOT; x < nBt; x += TOT) {
            const int p = listB[x];
            CELL1(p, locb)
        }
        float bs = bred(locb, t, s4);
        ++phase;
        float bacc = gbar2(leaf, lead, phase, b, t, bs);   // global black sum

        // ---------- red ----------
        float locr = 0.0f;
        SLOT_SWEEP2(ndR0, ssR0, vR0, pR0, dR00, dR01, dR02, dR03, dR04, dR05,
                    ndR1, ssR1, vR1, pR1, dR10, dR11, dR12, dR13, dR14, dR15, locr)
        for (int x = tid + 2 * TOT; x < nRt; x += TOT) {
            const int p = listR[x];
            CELL1(p, locr)
        }
        float rs = bred(locr, t, s4);
        ++phase;
        float racc = gbar2(leaf, lead, phase, b, t, rs);   // global red sum

        // ---------- dv = blackSum + redSum, broadcast ----------
        if (t == 0) s4[0] = __fadd_rn(bacc, racc);
        __syncthreads();
        dv = s4[0];          // identical in every block (fixed order)

        ++it;
    } while (dv >= 0.05f && it <= 500);

    // reader-less cells (nd==0) were never stored in the loop: store once now,
    // then one more barrier so every block sees all final values.
    if (pB0 >= 0 && ndB0 == 0) STV(&v[pB0], vB0);
    if (pB1 >= 0 && ndB1 == 0) STV(&v[pB1], vB1);
    if (pR0 >= 0 && ndR0 == 0) STV(&v[pR0], vR0);
    if (pR1 >= 0 && ndR1 == 0) STV(&v[pR1], vR1);
    ++phase;
    gbar2(leaf, lead, phase, b, t, 0.0f);

    // ---- epilogue (v read via bypass: caches hold no valid v lines) ----
    for (int g = tid; g < NG; g += TOT) {
        int i = g >> 14, j = (g >> 7) & 127, k = g & 127;
        out[g] = LDV(&v[(i + 1) * P2 + (j + 1) * P + (k + 1)]);
    }
    if (tid == 0) {
        out[NG]     = (float)it;
        out[NG + 1] = dv;
    }
}

extern "C" void kernel_launch(void* const* d_in, const int* in_sizes, int n_in,
                              void* d_out, int out_size, void* d_ws, size_t ws_size,
                              hipStream_t stream) {
    const float* img  = (const float*)d_in[0];
    const int*   sink = (const int*)d_in[2];   // sink_label (=3)
    float*       out  = (float*)d_out;

    char* ws = (char*)d_ws;
    size_t off = 0;
    float* v = (float*)(ws + off);
    off += (size_t)NPAD * sizeof(float);
    off = (off + 255) & ~(size_t)255;
    int* listB = (int*)(ws + off);
    off += (size_t)CAPC * sizeof(int);
    int* listR = (int*)(ws + off);
    off += (size_t)CAPC * sizeof(int);
    int* cntB = (int*)(ws + off);
    off += (size_t)NB * sizeof(int);
    int* cntR = (int*)(ws + off);
    off += (size_t)NB * sizeof(int);
    off = (off + 255) & ~(size_t)255;
    u64* leaf = (u64*)(ws + off);
    off += (size_t)2 * NB * sizeof(u64);
    off = (off + 255) & ~(size_t)255;
    u64* lead = (u64*)(ws + off);
    off += (size_t)2 * NLEAD * sizeof(u64);
    (void)ws_size; (void)in_sizes; (void)n_in; (void)out_size;

    void* args[] = { (void*)&img, (void*)&sink, (void*)&v,
                     (void*)&listB, (void*)&listR, (void*)&cntB, (void*)&cntR,
                     (void*)&leaf, (void*)&lead, (void*)&out };
    hipLaunchCooperativeKernel((const void*)sor_kernel, dim3(NB), dim3(NT),
                               args, 0, stream);
}